// Round 7
// baseline (777.829 us; speedup 1.0000x reference)
//
#include <hip/hip_runtime.h>
#include <hip/hip_bf16.h>

#define N_NODES  100000
#define N_EDGES  1600000
#define N_GRAPHS 128
#define HID      64
#define NBUCK    256
#define NPB      392                 // nodes per bucket: 256*392 = 100352 >= 100000
#define CAP      8192                // per-bucket record capacity (mean 6272, sd ~79)
#define BLKA     1024
#define EPTA     4
#define EPBA     (BLKA * EPTA)       // 4096 edges per pass-A block
#define NBLKA    ((N_EDGES + EPBA - 1) / EPBA)   // 391
#define AGST     65                  // l2 LDS agg row stride (floats) — bank spread

__device__ __forceinline__ float bl_lo(unsigned u) { return __uint_as_float(u << 16); }
__device__ __forceinline__ float bl_hi(unsigned u) { return __uint_as_float(u & 0xffff0000u); }

// ---------------- Pass A: block-local LDS counting sort into 256 dst-range buckets ----------------
__global__ __launch_bounds__(1024) void bucketA(const int* __restrict__ src,
                                                const int* __restrict__ dst,
                                                int* __restrict__ bcnt,      // [NBUCK*16], line-padded
                                                int2* __restrict__ bbuf) {   // [NBUCK*CAP]
    __shared__ int cnt[NBUCK], scn[NBUCK], cur[NBUCK], gb[NBUCK];
    __shared__ int2 srt[EPBA];                    // 32 KB
    int tid = threadIdx.x;
    if (tid < NBUCK) cnt[tid] = 0;
    __syncthreads();

    int e0 = (blockIdx.x * BLKA + tid) * EPTA;
    int s[EPTA], d[EPTA], b[EPTA];
    int nv = 0;
    if (e0 + EPTA <= N_EDGES) {
        int4 s4 = *reinterpret_cast<const int4*>(src + e0);
        int4 d4 = *reinterpret_cast<const int4*>(dst + e0);
        s[0] = s4.x; s[1] = s4.y; s[2] = s4.z; s[3] = s4.w;
        d[0] = d4.x; d[1] = d4.y; d[2] = d4.z; d[3] = d4.w;
        nv = EPTA;
    } else {
        for (int e = e0; e < N_EDGES; ++e) { s[nv] = src[e]; d[nv] = dst[e]; ++nv; }
    }
    for (int k = 0; k < nv; ++k) {
        b[k] = (int)((unsigned)d[k] / (unsigned)NPB);
        atomicAdd(&cnt[b[k]], 1);
    }
    __syncthreads();

    if (tid < NBUCK) scn[tid] = cnt[tid];
    __syncthreads();
    for (int o = 1; o < NBUCK; o <<= 1) {
        int v = 0;
        if (tid < NBUCK && tid >= o) v = scn[tid - o];
        __syncthreads();
        if (tid < NBUCK && tid >= o) scn[tid] += v;
        __syncthreads();
    }
    if (tid < NBUCK) {
        int ex = scn[tid] - cnt[tid];
        cur[tid] = ex;
        gb[tid] = (cnt[tid] > 0) ? atomicAdd(&bcnt[tid * 16], cnt[tid]) : 0;
        scn[tid] = ex;
    }
    __syncthreads();

    for (int k = 0; k < nv; ++k) {
        int p = atomicAdd(&cur[b[k]], 1);
        srt[p] = make_int2(s[k], d[k]);
    }
    __syncthreads();

    int tot = scn[NBUCK - 1] + cnt[NBUCK - 1];
    for (int i = tid; i < tot; i += BLKA) {
        int2 r = srt[i];
        int bb = (int)((unsigned)r.y / (unsigned)NPB);
        bbuf[(size_t)bb * CAP + gb[bb] + (i - scn[bb])] = r;
    }
}

// ---------------- Layer 1: bucket-resident LDS agg + MLP1 -> h1 (bf16) ----------------
__global__ __launch_bounds__(1024) void l1_bucket(const float* __restrict__ x,
                                                  const int2* __restrict__ bbuf,
                                                  const int* __restrict__ bcnt,
                                                  const float* __restrict__ W1a,
                                                  const float* __restrict__ b1a,
                                                  const float* __restrict__ W1b,
                                                  const float* __restrict__ b1b,
                                                  __hip_bfloat16* __restrict__ h1b) {
    __shared__ float agg[NPB * 3];                // 4.7 KB
    __shared__ float sWa[3 * 64];
    __shared__ float sWbT[64 * 66];               // sWbT[l][k] = W1b[k][l]
    __shared__ float sba[64], sbb[64];
    __shared__ float st_w[16][64];

    int b = blockIdx.x, tid = threadIdx.x;
    int node0 = b * NPB;
    int ncnt = N_NODES - node0; if (ncnt > NPB) ncnt = NPB;

    for (int i = tid; i < 3 * 64; i += 1024) sWa[i] = W1a[i];
    for (int i = tid; i < 64 * 64; i += 1024) { int k = i >> 6, l = i & 63; sWbT[l * 66 + k] = W1b[i]; }
    if (tid < 64) { sba[tid] = b1a[tid]; sbb[tid] = b1b[tid]; }
    // self init: agg = x rows of this bucket
    for (int i = tid; i < ncnt * 3; i += 1024) agg[i] = x[node0 * 3 + i];
    __syncthreads();

    int cnt = bcnt[b * 16];
    const int2* buf = bbuf + (size_t)b * CAP;
    for (int e = tid; e < cnt; e += 1024) {
        int2 r = buf[e];
        int loc = r.y - node0;
        float x0 = x[r.x * 3 + 0], x1 = x[r.x * 3 + 1], x2 = x[r.x * 3 + 2];
        unsafeAtomicAdd(&agg[loc * 3 + 0], x0);
        unsafeAtomicAdd(&agg[loc * 3 + 1], x1);
        unsafeAtomicAdd(&agg[loc * 3 + 2], x2);
    }
    __syncthreads();

    int w = tid >> 6, j = tid & 63;
    for (int nl = w; nl < ncnt; nl += 16) {
        float in0 = agg[nl * 3 + 0], in1 = agg[nl * 3 + 1], in2 = agg[nl * 3 + 2];
        float t = sba[j] + in0 * sWa[j] + in1 * sWa[64 + j] + in2 * sWa[128 + j];
        st_w[w][j] = fmaxf(t, 0.0f);
        __builtin_amdgcn_wave_barrier();
        float acc = sbb[j];
        const float* rowb = &sWbT[j * 66];
#pragma unroll
        for (int k = 0; k < 64; k += 2) {
            float2 wv = *reinterpret_cast<const float2*>(&rowb[k]);
            acc += st_w[w][k] * wv.x + st_w[w][k + 1] * wv.y;
        }
        h1b[(size_t)(node0 + nl) * 64 + j] = __float2bfloat16(fmaxf(acc, 0.0f));
        __builtin_amdgcn_wave_barrier();
    }
}

// ---------------- Layer 2: bucket-resident LDS agg (bf16 gather, fire-and-forget) + MLP2 -> h2 ----------------
__global__ __launch_bounds__(1024) void l2_bucket(const unsigned* __restrict__ h1p,  // [N_NODES*32] packed 2xbf16
                                                  const int2* __restrict__ bbuf,
                                                  const int* __restrict__ bcnt,
                                                  const float* __restrict__ W2a,
                                                  const float* __restrict__ b2a,
                                                  const float* __restrict__ W2b,
                                                  const float* __restrict__ b2b,
                                                  float* __restrict__ h2) {
    __shared__ float agg[NPB * AGST];             // 392*65*4 = 101,920 B
    __shared__ float sWaT[64 * 66];               // 16.9 KB
    __shared__ float sWbT[64 * 66];
    __shared__ float sba[64], sbb[64];
    __shared__ float st_w[16][64];                // 4 KB   -> total ~137 KB

    int b = blockIdx.x, tid = threadIdx.x;
    int node0 = b * NPB;
    int ncnt = N_NODES - node0; if (ncnt > NPB) ncnt = NPB;

    for (int i = tid; i < 64 * 64; i += 1024) {
        int k = i >> 6, l = i & 63;
        sWaT[l * 66 + k] = W2a[i];
        sWbT[l * 66 + k] = W2b[i];
    }
    if (tid < 64) { sba[tid] = b2a[tid]; sbb[tid] = b2b[tid]; }
    // self init: agg row = own h1 row
    for (int i = tid; i < ncnt * 32; i += 1024) {
        int nl = i >> 5, qq = i & 31;
        unsigned u = h1p[(size_t)(node0 + nl) * 32 + qq];
        agg[nl * AGST + 2 * qq]     = bl_lo(u);
        agg[nl * AGST + 2 * qq + 1] = bl_hi(u);
    }
    __syncthreads();

    int cnt = bcnt[b * 16];
    const int2* buf = bbuf + (size_t)b * CAP;
    int q = tid & 15;
    for (int e = tid >> 4; e < cnt; e += 64) {
        int2 r = buf[e];                          // broadcast across 16 lanes
        int loc = r.y - node0;
        unsigned u0 = h1p[(size_t)r.x * 32 + q];
        unsigned u1 = h1p[(size_t)r.x * 32 + q + 16];
        float* arow = &agg[loc * AGST];
        unsafeAtomicAdd(&arow[2 * q],      bl_lo(u0));
        unsafeAtomicAdd(&arow[2 * q + 1],  bl_hi(u0));
        unsafeAtomicAdd(&arow[2 * q + 32], bl_lo(u1));
        unsafeAtomicAdd(&arow[2 * q + 33], bl_hi(u1));
    }
    __syncthreads();

    int w = tid >> 6, l = tid & 63;
    for (int nl = w; nl < ncnt; nl += 16) {
        const float* arow = &agg[nl * AGST];
        float t = sba[l];
        const float* rowa = &sWaT[l * 66];
#pragma unroll
        for (int k = 0; k < 64; k += 2) {
            float2 wv = *reinterpret_cast<const float2*>(&rowa[k]);
            t += arow[k] * wv.x + arow[k + 1] * wv.y;
        }
        st_w[w][l] = fmaxf(t, 0.0f);
        __builtin_amdgcn_wave_barrier();
        float o = sbb[l];
        const float* rowb = &sWbT[l * 66];
#pragma unroll
        for (int k = 0; k < 64; k += 2) {
            float2 wv = *reinterpret_cast<const float2*>(&rowb[k]);
            o += st_w[w][k] * wv.x + st_w[w][k + 1] * wv.y;
        }
        h2[(size_t)(node0 + nl) * 64 + l] = fmaxf(o, 0.0f);
        __builtin_amdgcn_wave_barrier();
    }
}

// ---------------- Global mean pool ----------------
__global__ __launch_bounds__(256) void pool(const float* __restrict__ h2,
                                            const int* __restrict__ batch,
                                            float* __restrict__ out) {
    int g = blockIdx.x;
    int lo = 0, hi = N_NODES;
    while (lo < hi) { int mid = (lo + hi) >> 1; if (batch[mid] < g) lo = mid + 1; else hi = mid; }
    int start = lo;
    lo = start; hi = N_NODES;
    while (lo < hi) { int mid = (lo + hi) >> 1; if (batch[mid] < g + 1) lo = mid + 1; else hi = mid; }
    int end = lo;

    int j = threadIdx.x & 63;
    int r = threadIdx.x >> 6;
    float local = 0.0f;
    for (int n = start + r; n < end; n += 4)
        local += h2[(size_t)n * 64 + j];

    __shared__ float red[4][64];
    red[r][j] = local;
    __syncthreads();
    if (r == 0) {
        float s = red[0][j] + red[1][j] + red[2][j] + red[3][j];
        float cnt = (float)((end - start) > 1 ? (end - start) : 1);
        out[g * 64 + j] = s / cnt;
    }
}

extern "C" void kernel_launch(void* const* d_in, const int* in_sizes, int n_in,
                              void* d_out, int out_size, void* d_ws, size_t ws_size,
                              hipStream_t stream) {
    const float* x    = (const float*)d_in[0];
    const int*   ei   = (const int*)d_in[1];
    const int*   bat  = (const int*)d_in[2];
    const float* W1a  = (const float*)d_in[3];
    const float* b1a  = (const float*)d_in[4];
    const float* W1b  = (const float*)d_in[5];
    const float* b1b  = (const float*)d_in[6];
    const float* W2a  = (const float*)d_in[7];
    const float* b2a  = (const float*)d_in[8];
    const float* W2b  = (const float*)d_in[9];
    const float* b2b  = (const float*)d_in[10];
    float* out = (float*)d_out;

    const int* src = ei;
    const int* dst = ei + N_EDGES;

    char* ws = (char*)d_ws;
    auto alignup = [](size_t v) { return (v + 255) & ~(size_t)255; };
    int*   bcnt = (int*)ws;                        ws += alignup((size_t)NBUCK * 16 * 4);
    int2*  bbuf = (int2*)ws;                       ws += alignup((size_t)NBUCK * CAP * 8);   // 16.8 MB
    __hip_bfloat16* h1b = (__hip_bfloat16*)ws;     ws += alignup((size_t)N_NODES * HID * 2); // 12.8 MB
    float* h2   = (float*)ws;                      // 25.6 MB

    hipMemsetAsync(bcnt, 0, (size_t)NBUCK * 16 * 4, stream);

    bucketA<<<NBLKA, BLKA, 0, stream>>>(src, dst, bcnt, bbuf);
    l1_bucket<<<NBUCK, 1024, 0, stream>>>(x, bbuf, bcnt, W1a, b1a, W1b, b1b, h1b);
    l2_bucket<<<NBUCK, 1024, 0, stream>>>((const unsigned*)h1b, bbuf, bcnt, W2a, b2a, W2b, b2b, h2);
    pool<<<N_GRAPHS, 256, 0, stream>>>(h2, bat, out);
}

// Round 8
// 233.454 us; speedup vs baseline: 3.3318x; 3.3318x over previous
//
#include <hip/hip_runtime.h>
#include <hip/hip_bf16.h>

#define N_NODES  100000
#define N_EDGES  1600000
#define N_GRAPHS 128
#define HID      64
#define NBUCK    256
#define NPB      391                 // nodes per bucket: ceil(100000/256)
#define CAP      8192                // per-bucket record capacity (mean 6250)
#define BLKA     1024
#define EPTA     4
#define EPBA     (BLKA * EPTA)       // 4096 edges per pass-A block
#define NBLKA    ((N_EDGES + EPBA - 1) / EPBA)   // 391

#define NTILES   (N_NODES / 16)      // 6250 (exact)
#define BLK2     512
#define WPB2     (BLK2 / 64)         // 8 waves per block
#define NBLK2    512
#define NWAVES2  (NBLK2 * WPB2)      // 4096
#define TCW      256                 // per-tile fixed-cost weight for balancing

typedef short short8v __attribute__((ext_vector_type(8)));
typedef float float4v __attribute__((ext_vector_type(4)));

__device__ __forceinline__ float bl_lo(unsigned u) { return __uint_as_float(u << 16); }
__device__ __forceinline__ float bl_hi(unsigned u) { return __uint_as_float(u & 0xffff0000u); }
__device__ __forceinline__ unsigned short f2bf(float f) {
    unsigned u = __float_as_uint(f);
    u += 0x7fffu + ((u >> 16) & 1u);           // round-to-nearest-even
    return (unsigned short)(u >> 16);
}

// ---------------- Pass A: block-local LDS counting sort into 256 dst-range buckets ----------------
__global__ __launch_bounds__(1024) void bucketA(const int* __restrict__ src,
                                                const int* __restrict__ dst,
                                                int* __restrict__ bcnt,      // [NBUCK*16], line-padded
                                                int2* __restrict__ bbuf) {   // [NBUCK*CAP]
    __shared__ int cnt[NBUCK], scn[NBUCK], cur[NBUCK], gb[NBUCK];
    __shared__ int2 srt[EPBA];                    // 32 KB
    int tid = threadIdx.x;
    if (tid < NBUCK) cnt[tid] = 0;
    __syncthreads();

    int e0 = (blockIdx.x * BLKA + tid) * EPTA;
    int s[EPTA], d[EPTA], b[EPTA];
    int nv = 0;
    if (e0 + EPTA <= N_EDGES) {
        int4 s4 = *reinterpret_cast<const int4*>(src + e0);
        int4 d4 = *reinterpret_cast<const int4*>(dst + e0);
        s[0] = s4.x; s[1] = s4.y; s[2] = s4.z; s[3] = s4.w;
        d[0] = d4.x; d[1] = d4.y; d[2] = d4.z; d[3] = d4.w;
        nv = EPTA;
    } else {
        for (int e = e0; e < N_EDGES; ++e) { s[nv] = src[e]; d[nv] = dst[e]; ++nv; }
    }
    for (int k = 0; k < nv; ++k) {
        b[k] = (int)((unsigned)d[k] / (unsigned)NPB);
        atomicAdd(&cnt[b[k]], 1);
    }
    __syncthreads();

    if (tid < NBUCK) scn[tid] = cnt[tid];
    __syncthreads();
    for (int o = 1; o < NBUCK; o <<= 1) {
        int v = 0;
        if (tid < NBUCK && tid >= o) v = scn[tid - o];
        __syncthreads();
        if (tid < NBUCK && tid >= o) scn[tid] += v;
        __syncthreads();
    }
    if (tid < NBUCK) {
        int ex = scn[tid] - cnt[tid];
        cur[tid] = ex;
        gb[tid] = (cnt[tid] > 0) ? atomicAdd(&bcnt[tid * 16], cnt[tid]) : 0;
        scn[tid] = ex;
    }
    __syncthreads();

    for (int k = 0; k < nv; ++k) {
        int p = atomicAdd(&cur[b[k]], 1);
        srt[p] = make_int2(s[k], d[k]);
    }
    __syncthreads();

    int tot = scn[NBUCK - 1] + cnt[NBUCK - 1];
    for (int i = tid; i < tot; i += BLKA) {
        int2 r = srt[i];
        int bb = (int)((unsigned)r.y / (unsigned)NPB);
        bbuf[(size_t)bb * CAP + gb[bb] + (i - scn[bb])] = r;
    }
}

// ---------------- bucket base scan ----------------
__global__ __launch_bounds__(256) void scanBuck(const int* __restrict__ bcnt,
                                                int* __restrict__ bbase,
                                                int* __restrict__ off) {
    __shared__ int s[NBUCK];
    int t = threadIdx.x;
    int own = bcnt[t * 16];
    s[t] = own;
    __syncthreads();
    for (int o = 1; o < NBUCK; o <<= 1) {
        int v = (t >= o) ? s[t - o] : 0;
        __syncthreads();
        s[t] += v;
        __syncthreads();
    }
    bbase[t] = s[t] - own;
    if (t == NBUCK - 1) {
        bbase[NBUCK] = s[t];
        off[N_NODES] = s[t];
    }
}

// ---------------- Pass B: per-bucket CSR via LDS histogram + scan ----------------
__global__ __launch_bounds__(1024) void bucketB(const int2* __restrict__ bbuf,
                                                const int* __restrict__ bcnt,
                                                const int* __restrict__ bbase,
                                                int* __restrict__ off,
                                                int* __restrict__ esrc) {
    __shared__ int hist[NPB], scn[NPB], cur[NPB];
    int b = blockIdx.x, tid = threadIdx.x;
    int node0 = b * NPB;
    int ncnt = N_NODES - node0; if (ncnt > NPB) ncnt = NPB;
    if (tid < ncnt) hist[tid] = 0;
    __syncthreads();

    int cnt  = bcnt[b * 16];
    int base = bbase[b];
    const int2* buf = bbuf + (size_t)b * CAP;

    for (int i = tid; i < cnt; i += 1024)
        atomicAdd(&hist[buf[i].y - node0], 1);
    __syncthreads();

    if (tid < ncnt) scn[tid] = hist[tid];
    __syncthreads();
    for (int o = 1; o < NPB; o <<= 1) {
        int v = 0;
        if (tid < ncnt && tid >= o) v = scn[tid - o];
        __syncthreads();
        if (tid < ncnt && tid >= o) scn[tid] += v;
        __syncthreads();
    }
    if (tid < ncnt) {
        int ex = scn[tid] - hist[tid];
        off[node0 + tid] = base + ex;
        cur[tid] = ex;
    }
    __syncthreads();

    for (int i = tid; i < cnt; i += 1024) {
        int2 r = buf[i];
        int p = atomicAdd(&cur[r.y - node0], 1);
        esrc[base + p] = r.x;
    }
}

// ---------------- balanced tile partition: smallest t with off[16t]+TCW*t >= target ----------------
__device__ __forceinline__ int tile_bound(const int* __restrict__ off, long long target) {
    int lo = 0, hi = NTILES;
    while (lo < hi) {
        int mid = (lo + hi) >> 1;
        long long v = (long long)off[mid * 16] + (long long)TCW * mid;
        if (v < target) lo = mid + 1; else hi = mid;
    }
    return lo;
}

// ---------------- Layer 1: gather(x) + scalar layer-a + MFMA layer-b -> h1 (bf16) ----------------
__global__ __launch_bounds__(512, 8) void l1_mfma(const float* __restrict__ x,
                                                  const int* __restrict__ off,
                                                  const int* __restrict__ esrc,
                                                  const float* __restrict__ W1a,
                                                  const float* __restrict__ b1a,
                                                  const float* __restrict__ W1b,
                                                  const float* __restrict__ b1b,
                                                  unsigned short* __restrict__ h1b) {
    __shared__ float sWa[3 * 64];
    __shared__ float sba[64], sbb[64];
    __shared__ __align__(16) unsigned short sWbT[64 * 72];   // sWbT[n*72+k] = bf16(W1b[k][n])
    __shared__ __align__(16) unsigned short stA[WPB2][16][72];

    int tid = threadIdx.x;
    for (int i = tid; i < 3 * 64; i += BLK2) sWa[i] = W1a[i];
    for (int i = tid; i < 64 * 64; i += BLK2) {
        int k = i >> 6, n = i & 63;
        sWbT[n * 72 + k] = f2bf(W1b[i]);
    }
    if (tid < 64) { sba[tid] = b1a[tid]; sbb[tid] = b1b[tid]; }
    __syncthreads();

    int w = tid >> 6;
    int l = tid & 63;
    int m  = l & 15;          // A row / D col
    int kg = l >> 4;          // k-group / D row-group
    int wid = blockIdx.x * WPB2 + w;

    const long long TOT = (long long)N_EDGES + (long long)TCW * NTILES;
    int t0 = tile_bound(off, TOT * wid / NWAVES2);
    int t1 = tile_bound(off, TOT * (wid + 1) / NWAVES2);

    for (int t = t0; t < t1; ++t) {
        int nt0 = t * 16;
        for (int mm = 0; mm < 16; ++mm) {
            int n = nt0 + mm;
            int start = off[n], end = off[n + 1];
            float a0 = 0.f, a1 = 0.f, a2 = 0.f;
            for (int e = start + l; e < end; e += 64) {
                int s = esrc[e];
                a0 += x[s * 3 + 0];
                a1 += x[s * 3 + 1];
                a2 += x[s * 3 + 2];
            }
#pragma unroll
            for (int d = 1; d < 64; d <<= 1) {
                a0 += __shfl_xor(a0, d);
                a1 += __shfl_xor(a1, d);
                a2 += __shfl_xor(a2, d);
            }
            float in0 = x[n * 3 + 0] + a0;
            float in1 = x[n * 3 + 1] + a1;
            float in2 = x[n * 3 + 2] + a2;
            float tt = sba[l] + in0 * sWa[l] + in1 * sWa[64 + l] + in2 * sWa[128 + l];
            stA[w][mm][l] = f2bf(fmaxf(tt, 0.0f));
        }
        __builtin_amdgcn_wave_barrier();

        short8v A0 = *reinterpret_cast<const short8v*>(&stA[w][m][kg * 8]);
        short8v A1 = *reinterpret_cast<const short8v*>(&stA[w][m][32 + kg * 8]);
#pragma unroll
        for (int c = 0; c < 4; ++c) {
            short8v B0 = *reinterpret_cast<const short8v*>(&sWbT[(16 * c + m) * 72 + kg * 8]);
            short8v B1 = *reinterpret_cast<const short8v*>(&sWbT[(16 * c + m) * 72 + 32 + kg * 8]);
            float bb = sbb[16 * c + m];
            float4v acc = {bb, bb, bb, bb};
            acc = __builtin_amdgcn_mfma_f32_16x16x32_bf16(A0, B0, acc, 0, 0, 0);
            acc = __builtin_amdgcn_mfma_f32_16x16x32_bf16(A1, B1, acc, 0, 0, 0);
#pragma unroll
            for (int i = 0; i < 4; ++i)
                h1b[(size_t)(nt0 + kg * 4 + i) * 64 + 16 * c + m] = f2bf(fmaxf(acc[i], 0.0f));
        }
        __builtin_amdgcn_wave_barrier();
    }
}

// ---------------- Layer 2: bf16 gather + double MFMA MLP -> h2 (f32) ----------------
__global__ __launch_bounds__(512, 8) void l2_mfma(const unsigned* __restrict__ h1p,   // packed 2xbf16
                                                  const int* __restrict__ off,
                                                  const int* __restrict__ esrc,
                                                  const float* __restrict__ W2a,
                                                  const float* __restrict__ b2a,
                                                  const float* __restrict__ W2b,
                                                  const float* __restrict__ b2b,
                                                  float* __restrict__ h2) {
    __shared__ float sba[64], sbb[64];
    __shared__ __align__(16) unsigned short sWaT[64 * 72];   // sWaT[n*72+k] = bf16(W2a[k][n])
    __shared__ __align__(16) unsigned short sWbT[64 * 72];
    __shared__ __align__(16) unsigned short stA[WPB2][16][72];

    int tid = threadIdx.x;
    for (int i = tid; i < 64 * 64; i += BLK2) {
        int k = i >> 6, n = i & 63;
        sWaT[n * 72 + k] = f2bf(W2a[i]);
        sWbT[n * 72 + k] = f2bf(W2b[i]);
    }
    if (tid < 64) { sba[tid] = b2a[tid]; sbb[tid] = b2b[tid]; }
    __syncthreads();

    int w = tid >> 6;
    int l = tid & 63;
    int g = l >> 4;          // edge slot 0..3
    int q = l & 15;          // 8B chunk of 128B row
    int m  = l & 15;
    int kg = l >> 4;
    int wid = blockIdx.x * WPB2 + w;

    const long long TOT = (long long)N_EDGES + (long long)TCW * NTILES;
    int t0 = tile_bound(off, TOT * wid / NWAVES2);
    int t1 = tile_bound(off, TOT * (wid + 1) / NWAVES2);

    for (int t = t0; t < t1; ++t) {
        int nt0 = t * 16;
        // ---- gather 16 nodes -> stA rows (bf16) ----
        for (int mm = 0; mm < 16; ++mm) {
            int n = nt0 + mm;
            int start = off[n], end = off[n + 1];
            float a0 = 0.f, a1 = 0.f, a2 = 0.f, a3 = 0.f;
            if (g == 0) {      // self term once
                uint2 v = *reinterpret_cast<const uint2*>(h1p + (size_t)n * 32 + 2 * q);
                a0 += bl_lo(v.x); a1 += bl_hi(v.x); a2 += bl_lo(v.y); a3 += bl_hi(v.y);
            }
            int e = start + g;
            for (; e + 4 < end; e += 8) {
                int s0 = esrc[e];
                int s1 = esrc[e + 4];
                uint2 v0 = *reinterpret_cast<const uint2*>(h1p + (size_t)s0 * 32 + 2 * q);
                uint2 v1 = *reinterpret_cast<const uint2*>(h1p + (size_t)s1 * 32 + 2 * q);
                a0 += bl_lo(v0.x) + bl_lo(v1.x);
                a1 += bl_hi(v0.x) + bl_hi(v1.x);
                a2 += bl_lo(v0.y) + bl_lo(v1.y);
                a3 += bl_hi(v0.y) + bl_hi(v1.y);
            }
            if (e < end) {
                int s0 = esrc[e];
                uint2 v0 = *reinterpret_cast<const uint2*>(h1p + (size_t)s0 * 32 + 2 * q);
                a0 += bl_lo(v0.x); a1 += bl_hi(v0.x); a2 += bl_lo(v0.y); a3 += bl_hi(v0.y);
            }
            a0 += __shfl_xor(a0, 16); a0 += __shfl_xor(a0, 32);
            a1 += __shfl_xor(a1, 16); a1 += __shfl_xor(a1, 32);
            a2 += __shfl_xor(a2, 16); a2 += __shfl_xor(a2, 32);
            a3 += __shfl_xor(a3, 16); a3 += __shfl_xor(a3, 32);
            if (g == 0) {
                uint2 pk;
                pk.x = ((unsigned)f2bf(a1) << 16) | (unsigned)f2bf(a0);
                pk.y = ((unsigned)f2bf(a3) << 16) | (unsigned)f2bf(a2);
                *reinterpret_cast<uint2*>(&stA[w][mm][4 * q]) = pk;
            }
        }
        __builtin_amdgcn_wave_barrier();

        // ---- matmul1: relu(agg @ W2a + b2a), restage as bf16 ----
        short8v A0 = *reinterpret_cast<const short8v*>(&stA[w][m][kg * 8]);
        short8v A1 = *reinterpret_cast<const short8v*>(&stA[w][m][32 + kg * 8]);
#pragma unroll
        for (int c = 0; c < 4; ++c) {
            short8v B0 = *reinterpret_cast<const short8v*>(&sWaT[(16 * c + m) * 72 + kg * 8]);
            short8v B1 = *reinterpret_cast<const short8v*>(&sWaT[(16 * c + m) * 72 + 32 + kg * 8]);
            float bb = sba[16 * c + m];
            float4v acc = {bb, bb, bb, bb};
            acc = __builtin_amdgcn_mfma_f32_16x16x32_bf16(A0, B0, acc, 0, 0, 0);
            acc = __builtin_amdgcn_mfma_f32_16x16x32_bf16(A1, B1, acc, 0, 0, 0);
#pragma unroll
            for (int i = 0; i < 4; ++i)
                stA[w][kg * 4 + i][16 * c + m] = f2bf(fmaxf(acc[i], 0.0f));
        }
        __builtin_amdgcn_wave_barrier();

        // ---- matmul2: relu(h @ W2b + b2b) -> h2 ----
        short8v C0 = *reinterpret_cast<const short8v*>(&stA[w][m][kg * 8]);
        short8v C1 = *reinterpret_cast<const short8v*>(&stA[w][m][32 + kg * 8]);
#pragma unroll
        for (int c = 0; c < 4; ++c) {
            short8v B0 = *reinterpret_cast<const short8v*>(&sWbT[(16 * c + m) * 72 + kg * 8]);
            short8v B1 = *reinterpret_cast<const short8v*>(&sWbT[(16 * c + m) * 72 + 32 + kg * 8]);
            float bb = sbb[16 * c + m];
            float4v acc = {bb, bb, bb, bb};
            acc = __builtin_amdgcn_mfma_f32_16x16x32_bf16(C0, B0, acc, 0, 0, 0);
            acc = __builtin_amdgcn_mfma_f32_16x16x32_bf16(C1, B1, acc, 0, 0, 0);
#pragma unroll
            for (int i = 0; i < 4; ++i)
                h2[(size_t)(nt0 + kg * 4 + i) * 64 + 16 * c + m] = fmaxf(acc[i], 0.0f);
        }
        __builtin_amdgcn_wave_barrier();
    }
}

// ---------------- Global mean pool ----------------
__global__ __launch_bounds__(256) void pool(const float* __restrict__ h2,
                                            const int* __restrict__ batch,
                                            float* __restrict__ out) {
    int g = blockIdx.x;
    int lo = 0, hi = N_NODES;
    while (lo < hi) { int mid = (lo + hi) >> 1; if (batch[mid] < g) lo = mid + 1; else hi = mid; }
    int start = lo;
    lo = start; hi = N_NODES;
    while (lo < hi) { int mid = (lo + hi) >> 1; if (batch[mid] < g + 1) lo = mid + 1; else hi = mid; }
    int end = lo;

    int j = threadIdx.x & 63;
    int r = threadIdx.x >> 6;
    float local = 0.0f;
    for (int n = start + r; n < end; n += 4)
        local += h2[(size_t)n * 64 + j];

    __shared__ float red[4][64];
    red[r][j] = local;
    __syncthreads();
    if (r == 0) {
        float s = red[0][j] + red[1][j] + red[2][j] + red[3][j];
        float cnt = (float)((end - start) > 1 ? (end - start) : 1);
        out[g * 64 + j] = s / cnt;
    }
}

extern "C" void kernel_launch(void* const* d_in, const int* in_sizes, int n_in,
                              void* d_out, int out_size, void* d_ws, size_t ws_size,
                              hipStream_t stream) {
    const float* x    = (const float*)d_in[0];
    const int*   ei   = (const int*)d_in[1];
    const int*   bat  = (const int*)d_in[2];
    const float* W1a  = (const float*)d_in[3];
    const float* b1a  = (const float*)d_in[4];
    const float* W1b  = (const float*)d_in[5];
    const float* b1b  = (const float*)d_in[6];
    const float* W2a  = (const float*)d_in[7];
    const float* b2a  = (const float*)d_in[8];
    const float* W2b  = (const float*)d_in[9];
    const float* b2b  = (const float*)d_in[10];
    float* out = (float*)d_out;

    const int* src = ei;
    const int* dst = ei + N_EDGES;

    char* ws = (char*)d_ws;
    auto alignup = [](size_t v) { return (v + 255) & ~(size_t)255; };
    int*   bcnt  = (int*)ws;                       ws += alignup((size_t)NBUCK * 16 * 4);
    int*   bbase = (int*)ws;                       ws += alignup((size_t)(NBUCK + 1) * 4);
    int*   off   = (int*)ws;                       ws += alignup((size_t)(N_NODES + 1) * 4);
    int*   esrc  = (int*)ws;                       ws += alignup((size_t)N_EDGES * 4);
    unsigned short* h1b = (unsigned short*)ws;     ws += alignup((size_t)N_NODES * HID * 2);
    // bbuf and h2 share a slab: bbuf dead before l2_mfma writes h2
    int2*  bbuf  = (int2*)ws;
    float* h2    = (float*)ws;

    hipMemsetAsync(bcnt, 0, (size_t)NBUCK * 16 * 4, stream);

    bucketA<<<NBLKA, BLKA, 0, stream>>>(src, dst, bcnt, bbuf);
    scanBuck<<<1, 256, 0, stream>>>(bcnt, bbase, off);
    bucketB<<<NBUCK, 1024, 0, stream>>>(bbuf, bcnt, bbase, off, esrc);

    l1_mfma<<<NBLK2, BLK2, 0, stream>>>(x, off, esrc, W1a, b1a, W1b, b1b, h1b);
    l2_mfma<<<NBLK2, BLK2, 0, stream>>>((const unsigned*)h1b, off, esrc, W2a, b2a, W2b, b2b, h2);
    pool<<<N_GRAPHS, 256, 0, stream>>>(h2, bat, out);
}

// Round 9
// 190.353 us; speedup vs baseline: 4.0862x; 1.2264x over previous
//
#include <hip/hip_runtime.h>
#include <hip/hip_bf16.h>

#define N_NODES  100000
#define N_EDGES  1600000
#define N_GRAPHS 128
#define HID      64
#define NBUCK    256
#define NPB      391                 // nodes per bucket: ceil(100000/256)
#define CAP      8192                // per-bucket record capacity (mean 6250)
#define BLKA     1024
#define EPTA     4
#define EPBA     (BLKA * EPTA)       // 4096 edges per pass-A block
#define NBLKA    ((N_EDGES + EPBA - 1) / EPBA)   // 391

#define NTILES   (N_NODES / 16)      // 6250 (exact)
#define BLK2     512
#define WPB2     (BLK2 / 64)         // 8 waves per block
#define NBLK2    1024                // 8192 waves = 100% occupancy cap
#define NWAVES2  (NBLK2 * WPB2)      // 8192
#define TCW      256                 // per-tile fixed-cost weight for balancing

typedef short short8v __attribute__((ext_vector_type(8)));
typedef float float4v __attribute__((ext_vector_type(4)));

__device__ __forceinline__ float bl_lo(unsigned u) { return __uint_as_float(u << 16); }
__device__ __forceinline__ float bl_hi(unsigned u) { return __uint_as_float(u & 0xffff0000u); }
__device__ __forceinline__ unsigned short f2bf(float f) {
    unsigned u = __float_as_uint(f);
    u += 0x7fffu + ((u >> 16) & 1u);           // round-to-nearest-even
    return (unsigned short)(u >> 16);
}

// ---------------- Pass A: block-local LDS counting sort into 256 dst-range buckets ----------------
__global__ __launch_bounds__(1024) void bucketA(const int* __restrict__ src,
                                                const int* __restrict__ dst,
                                                int* __restrict__ bcnt,      // [NBUCK*16], line-padded
                                                int2* __restrict__ bbuf) {   // [NBUCK*CAP]
    __shared__ int cnt[NBUCK], scn[NBUCK], cur[NBUCK], gb[NBUCK];
    __shared__ int2 srt[EPBA];                    // 32 KB
    int tid = threadIdx.x;
    if (tid < NBUCK) cnt[tid] = 0;
    __syncthreads();

    int e0 = (blockIdx.x * BLKA + tid) * EPTA;
    int s[EPTA], d[EPTA], b[EPTA];
    int nv = 0;
    if (e0 + EPTA <= N_EDGES) {
        int4 s4 = *reinterpret_cast<const int4*>(src + e0);
        int4 d4 = *reinterpret_cast<const int4*>(dst + e0);
        s[0] = s4.x; s[1] = s4.y; s[2] = s4.z; s[3] = s4.w;
        d[0] = d4.x; d[1] = d4.y; d[2] = d4.z; d[3] = d4.w;
        nv = EPTA;
    } else {
        for (int e = e0; e < N_EDGES; ++e) { s[nv] = src[e]; d[nv] = dst[e]; ++nv; }
    }
    for (int k = 0; k < nv; ++k) {
        b[k] = (int)((unsigned)d[k] / (unsigned)NPB);
        atomicAdd(&cnt[b[k]], 1);
    }
    __syncthreads();

    if (tid < NBUCK) scn[tid] = cnt[tid];
    __syncthreads();
    for (int o = 1; o < NBUCK; o <<= 1) {
        int v = 0;
        if (tid < NBUCK && tid >= o) v = scn[tid - o];
        __syncthreads();
        if (tid < NBUCK && tid >= o) scn[tid] += v;
        __syncthreads();
    }
    if (tid < NBUCK) {
        int ex = scn[tid] - cnt[tid];
        cur[tid] = ex;
        gb[tid] = (cnt[tid] > 0) ? atomicAdd(&bcnt[tid * 16], cnt[tid]) : 0;
        scn[tid] = ex;
    }
    __syncthreads();

    for (int k = 0; k < nv; ++k) {
        int p = atomicAdd(&cur[b[k]], 1);
        srt[p] = make_int2(s[k], d[k]);
    }
    __syncthreads();

    int tot = scn[NBUCK - 1] + cnt[NBUCK - 1];
    for (int i = tid; i < tot; i += BLKA) {
        int2 r = srt[i];
        int bb = (int)((unsigned)r.y / (unsigned)NPB);
        bbuf[(size_t)bb * CAP + gb[bb] + (i - scn[bb])] = r;
    }
}

// ---------------- bucket base scan ----------------
__global__ __launch_bounds__(256) void scanBuck(const int* __restrict__ bcnt,
                                                int* __restrict__ bbase,
                                                int* __restrict__ off) {
    __shared__ int s[NBUCK];
    int t = threadIdx.x;
    int own = bcnt[t * 16];
    s[t] = own;
    __syncthreads();
    for (int o = 1; o < NBUCK; o <<= 1) {
        int v = (t >= o) ? s[t - o] : 0;
        __syncthreads();
        s[t] += v;
        __syncthreads();
    }
    bbase[t] = s[t] - own;
    if (t == NBUCK - 1) {
        bbase[NBUCK] = s[t];
        off[N_NODES] = s[t];
    }
}

// ---------------- Pass B: per-bucket CSR via LDS histogram + scan ----------------
__global__ __launch_bounds__(1024) void bucketB(const int2* __restrict__ bbuf,
                                                const int* __restrict__ bcnt,
                                                const int* __restrict__ bbase,
                                                int* __restrict__ off,
                                                int* __restrict__ esrc) {
    __shared__ int hist[NPB], scn[NPB], cur[NPB];
    int b = blockIdx.x, tid = threadIdx.x;
    int node0 = b * NPB;
    int ncnt = N_NODES - node0; if (ncnt > NPB) ncnt = NPB;
    if (tid < ncnt) hist[tid] = 0;
    __syncthreads();

    int cnt  = bcnt[b * 16];
    int base = bbase[b];
    const int2* buf = bbuf + (size_t)b * CAP;

    for (int i = tid; i < cnt; i += 1024)
        atomicAdd(&hist[buf[i].y - node0], 1);
    __syncthreads();

    if (tid < ncnt) scn[tid] = hist[tid];
    __syncthreads();
    for (int o = 1; o < NPB; o <<= 1) {
        int v = 0;
        if (tid < ncnt && tid >= o) v = scn[tid - o];
        __syncthreads();
        if (tid < ncnt && tid >= o) scn[tid] += v;
        __syncthreads();
    }
    if (tid < ncnt) {
        int ex = scn[tid] - hist[tid];
        off[node0 + tid] = base + ex;
        cur[tid] = ex;
    }
    __syncthreads();

    for (int i = tid; i < cnt; i += 1024) {
        int2 r = buf[i];
        int p = atomicAdd(&cur[r.y - node0], 1);
        esrc[base + p] = r.x;
    }
}

// ---------------- balanced tile partition: smallest t with off[16t]+TCW*t >= target ----------------
__device__ __forceinline__ int tile_bound(const int* __restrict__ off, long long target) {
    int lo = 0, hi = NTILES;
    while (lo < hi) {
        int mid = (lo + hi) >> 1;
        long long v = (long long)off[mid * 16] + (long long)TCW * mid;
        if (v < target) lo = mid + 1; else hi = mid;
    }
    return lo;
}

// ---------------- Layer 1: parallel gather(x) + scalar layer-a + MFMA layer-b -> h1 (bf16) ----------------
__global__ __launch_bounds__(512, 8) void l1_mfma(const float* __restrict__ x,
                                                  const int* __restrict__ off,
                                                  const int* __restrict__ esrc,
                                                  const float* __restrict__ W1a,
                                                  const float* __restrict__ b1a,
                                                  const float* __restrict__ W1b,
                                                  const float* __restrict__ b1b,
                                                  unsigned short* __restrict__ h1b) {
    __shared__ float sWa[3 * 64];
    __shared__ float sba[64], sbb[64];
    __shared__ __align__(16) unsigned short sWbT[64 * 72];   // sWbT[n*72+k] = bf16(W1b[k][n])
    __shared__ __align__(16) unsigned short stA[WPB2][16][72];

    int tid = threadIdx.x;
    for (int i = tid; i < 3 * 64; i += BLK2) sWa[i] = W1a[i];
    for (int i = tid; i < 64 * 64; i += BLK2) {
        int k = i >> 6, n = i & 63;
        sWbT[n * 72 + k] = f2bf(W1b[i]);
    }
    if (tid < 64) { sba[tid] = b1a[tid]; sbb[tid] = b1b[tid]; }
    __syncthreads();

    int w = tid >> 6;
    int l = tid & 63;
    int c  = l & 3;           // component 0..2 (lane c==3 contributes 0)
    int cc = (c < 3) ? c : 0;
    int ei = l >> 2;          // edge slot 0..15
    int m  = l & 15;          // A row / D col
    int kg = l >> 4;          // k-group / D row-group
    int wid = blockIdx.x * WPB2 + w;

    const long long TOT = (long long)N_EDGES + (long long)TCW * NTILES;
    int t0 = tile_bound(off, TOT * wid / NWAVES2);
    int t1 = tile_bound(off, TOT * (wid + 1) / NWAVES2);

    for (int t = t0; t < t1; ++t) {
        int nt0 = t * 16;
        for (int mm = 0; mm < 16; ++mm) {
            int n = nt0 + mm;
            int start = off[n], end = off[n + 1];
            float a = 0.f;
            for (int eb = start; eb < end; eb += 16) {
                int e = eb + ei;
                int es = e < end ? e : end - 1;
                int s = esrc[es];
                float v = x[s * 3 + cc];
                if (c == 3 || e >= end) v = 0.f;
                a += v;
            }
#pragma unroll
            for (int d = 4; d < 64; d <<= 1) a += __shfl_xor(a, d);
            float in0 = __shfl(a, 0) + x[n * 3 + 0];
            float in1 = __shfl(a, 1) + x[n * 3 + 1];
            float in2 = __shfl(a, 2) + x[n * 3 + 2];
            float tt = sba[l] + in0 * sWa[l] + in1 * sWa[64 + l] + in2 * sWa[128 + l];
            stA[w][mm][l] = f2bf(fmaxf(tt, 0.0f));
        }
        __builtin_amdgcn_wave_barrier();

        short8v A0 = *reinterpret_cast<const short8v*>(&stA[w][m][kg * 8]);
        short8v A1 = *reinterpret_cast<const short8v*>(&stA[w][m][32 + kg * 8]);
#pragma unroll
        for (int cq = 0; cq < 4; ++cq) {
            short8v B0 = *reinterpret_cast<const short8v*>(&sWbT[(16 * cq + m) * 72 + kg * 8]);
            short8v B1 = *reinterpret_cast<const short8v*>(&sWbT[(16 * cq + m) * 72 + 32 + kg * 8]);
            float bb = sbb[16 * cq + m];
            float4v acc = {bb, bb, bb, bb};
            acc = __builtin_amdgcn_mfma_f32_16x16x32_bf16(A0, B0, acc, 0, 0, 0);
            acc = __builtin_amdgcn_mfma_f32_16x16x32_bf16(A1, B1, acc, 0, 0, 0);
#pragma unroll
            for (int i = 0; i < 4; ++i)
                h1b[(size_t)(nt0 + kg * 4 + i) * 64 + 16 * cq + m] = f2bf(fmaxf(acc[i], 0.0f));
        }
        __builtin_amdgcn_wave_barrier();
    }
}

// ---------------- Layer 2: deep-unrolled bf16 gather + double MFMA MLP -> h2 (f32) ----------------
__global__ __launch_bounds__(512, 8) void l2_mfma(const unsigned* __restrict__ h1p,   // packed 2xbf16
                                                  const int* __restrict__ off,
                                                  const int* __restrict__ esrc,
                                                  const float* __restrict__ W2a,
                                                  const float* __restrict__ b2a,
                                                  const float* __restrict__ W2b,
                                                  const float* __restrict__ b2b,
                                                  float* __restrict__ h2) {
    __shared__ float sba[64], sbb[64];
    __shared__ __align__(16) unsigned short sWaT[64 * 72];   // sWaT[n*72+k] = bf16(W2a[k][n])
    __shared__ __align__(16) unsigned short sWbT[64 * 72];
    __shared__ __align__(16) unsigned short stA[WPB2][16][72];

    int tid = threadIdx.x;
    for (int i = tid; i < 64 * 64; i += BLK2) {
        int k = i >> 6, n = i & 63;
        sWaT[n * 72 + k] = f2bf(W2a[i]);
        sWbT[n * 72 + k] = f2bf(W2b[i]);
    }
    if (tid < 64) { sba[tid] = b2a[tid]; sbb[tid] = b2b[tid]; }
    __syncthreads();

    int w = tid >> 6;
    int l = tid & 63;
    int g = l >> 4;          // edge slot 0..3
    int q = l & 15;          // 8B chunk of 128B row
    int m  = l & 15;
    int kg = l >> 4;
    int wid = blockIdx.x * WPB2 + w;

    const long long TOT = (long long)N_EDGES + (long long)TCW * NTILES;
    int t0 = tile_bound(off, TOT * wid / NWAVES2);
    int t1 = tile_bound(off, TOT * (wid + 1) / NWAVES2);

    for (int t = t0; t < t1; ++t) {
        int nt0 = t * 16;
        // ---- gather 16 nodes -> stA rows (bf16) ----
        for (int mm = 0; mm < 16; ++mm) {
            int n = nt0 + mm;
            int start = off[n], end = off[n + 1];
            float a0 = 0.f, a1 = 0.f, a2 = 0.f, a3 = 0.f;
            if (g == 0) {      // self term once
                uint2 v = *reinterpret_cast<const uint2*>(h1p + (size_t)n * 32 + 2 * q);
                a0 += bl_lo(v.x); a1 += bl_hi(v.x); a2 += bl_lo(v.y); a3 += bl_hi(v.y);
            }
            for (int e = start; e < end; e += 16) {
                int tA = e + g, tB = e + 4 + g, tC = e + 8 + g, tD = e + 12 + g;
                int iA = tA < end ? tA : end - 1;
                int iB = tB < end ? tB : end - 1;
                int iC = tC < end ? tC : end - 1;
                int iD = tD < end ? tD : end - 1;
                int sA = esrc[iA], sB = esrc[iB], sC = esrc[iC], sD = esrc[iD];
                uint2 vA = *reinterpret_cast<const uint2*>(h1p + (size_t)sA * 32 + 2 * q);
                uint2 vB = *reinterpret_cast<const uint2*>(h1p + (size_t)sB * 32 + 2 * q);
                uint2 vC = *reinterpret_cast<const uint2*>(h1p + (size_t)sC * 32 + 2 * q);
                uint2 vD = *reinterpret_cast<const uint2*>(h1p + (size_t)sD * 32 + 2 * q);
                unsigned mA = tA < end ? 0xffffffffu : 0u;
                unsigned mB = tB < end ? 0xffffffffu : 0u;
                unsigned mC = tC < end ? 0xffffffffu : 0u;
                unsigned mD = tD < end ? 0xffffffffu : 0u;
                a0 += (bl_lo(vA.x & mA) + bl_lo(vB.x & mB)) + (bl_lo(vC.x & mC) + bl_lo(vD.x & mD));
                a1 += (bl_hi(vA.x & mA) + bl_hi(vB.x & mB)) + (bl_hi(vC.x & mC) + bl_hi(vD.x & mD));
                a2 += (bl_lo(vA.y & mA) + bl_lo(vB.y & mB)) + (bl_lo(vC.y & mC) + bl_lo(vD.y & mD));
                a3 += (bl_hi(vA.y & mA) + bl_hi(vB.y & mB)) + (bl_hi(vC.y & mC) + bl_hi(vD.y & mD));
            }
            a0 += __shfl_xor(a0, 16); a0 += __shfl_xor(a0, 32);
            a1 += __shfl_xor(a1, 16); a1 += __shfl_xor(a1, 32);
            a2 += __shfl_xor(a2, 16); a2 += __shfl_xor(a2, 32);
            a3 += __shfl_xor(a3, 16); a3 += __shfl_xor(a3, 32);
            if (g == 0) {
                uint2 pk;
                pk.x = ((unsigned)f2bf(a1) << 16) | (unsigned)f2bf(a0);
                pk.y = ((unsigned)f2bf(a3) << 16) | (unsigned)f2bf(a2);
                *reinterpret_cast<uint2*>(&stA[w][mm][4 * q]) = pk;
            }
        }
        __builtin_amdgcn_wave_barrier();

        // ---- matmul1: relu(agg @ W2a + b2a), restage as bf16 ----
        short8v A0 = *reinterpret_cast<const short8v*>(&stA[w][m][kg * 8]);
        short8v A1 = *reinterpret_cast<const short8v*>(&stA[w][m][32 + kg * 8]);
#pragma unroll
        for (int cq = 0; cq < 4; ++cq) {
            short8v B0 = *reinterpret_cast<const short8v*>(&sWaT[(16 * cq + m) * 72 + kg * 8]);
            short8v B1 = *reinterpret_cast<const short8v*>(&sWaT[(16 * cq + m) * 72 + 32 + kg * 8]);
            float bb = sba[16 * cq + m];
            float4v acc = {bb, bb, bb, bb};
            acc = __builtin_amdgcn_mfma_f32_16x16x32_bf16(A0, B0, acc, 0, 0, 0);
            acc = __builtin_amdgcn_mfma_f32_16x16x32_bf16(A1, B1, acc, 0, 0, 0);
#pragma unroll
            for (int i = 0; i < 4; ++i)
                stA[w][kg * 4 + i][16 * cq + m] = f2bf(fmaxf(acc[i], 0.0f));
        }
        __builtin_amdgcn_wave_barrier();

        // ---- matmul2: relu(h @ W2b + b2b) -> h2 ----
        short8v C0 = *reinterpret_cast<const short8v*>(&stA[w][m][kg * 8]);
        short8v C1 = *reinterpret_cast<const short8v*>(&stA[w][m][32 + kg * 8]);
#pragma unroll
        for (int cq = 0; cq < 4; ++cq) {
            short8v B0 = *reinterpret_cast<const short8v*>(&sWbT[(16 * cq + m) * 72 + kg * 8]);
            short8v B1 = *reinterpret_cast<const short8v*>(&sWbT[(16 * cq + m) * 72 + 32 + kg * 8]);
            float bb = sbb[16 * cq + m];
            float4v acc = {bb, bb, bb, bb};
            acc = __builtin_amdgcn_mfma_f32_16x16x32_bf16(C0, B0, acc, 0, 0, 0);
            acc = __builtin_amdgcn_mfma_f32_16x16x32_bf16(C1, B1, acc, 0, 0, 0);
#pragma unroll
            for (int i = 0; i < 4; ++i)
                h2[(size_t)(nt0 + kg * 4 + i) * 64 + 16 * cq + m] = fmaxf(acc[i], 0.0f);
        }
        __builtin_amdgcn_wave_barrier();
    }
}

// ---------------- Global mean pool ----------------
__global__ __launch_bounds__(256) void pool(const float* __restrict__ h2,
                                            const int* __restrict__ batch,
                                            float* __restrict__ out) {
    int g = blockIdx.x;
    int lo = 0, hi = N_NODES;
    while (lo < hi) { int mid = (lo + hi) >> 1; if (batch[mid] < g) lo = mid + 1; else hi = mid; }
    int start = lo;
    lo = start; hi = N_NODES;
    while (lo < hi) { int mid = (lo + hi) >> 1; if (batch[mid] < g + 1) lo = mid + 1; else hi = mid; }
    int end = lo;

    int j = threadIdx.x & 63;
    int r = threadIdx.x >> 6;
    float local = 0.0f;
    for (int n = start + r; n < end; n += 4)
        local += h2[(size_t)n * 64 + j];

    __shared__ float red[4][64];
    red[r][j] = local;
    __syncthreads();
    if (r == 0) {
        float s = red[0][j] + red[1][j] + red[2][j] + red[3][j];
        float cnt = (float)((end - start) > 1 ? (end - start) : 1);
        out[g * 64 + j] = s / cnt;
    }
}

extern "C" void kernel_launch(void* const* d_in, const int* in_sizes, int n_in,
                              void* d_out, int out_size, void* d_ws, size_t ws_size,
                              hipStream_t stream) {
    const float* x    = (const float*)d_in[0];
    const int*   ei   = (const int*)d_in[1];
    const int*   bat  = (const int*)d_in[2];
    const float* W1a  = (const float*)d_in[3];
    const float* b1a  = (const float*)d_in[4];
    const float* W1b  = (const float*)d_in[5];
    const float* b1b  = (const float*)d_in[6];
    const float* W2a  = (const float*)d_in[7];
    const float* b2a  = (const float*)d_in[8];
    const float* W2b  = (const float*)d_in[9];
    const float* b2b  = (const float*)d_in[10];
    float* out = (float*)d_out;

    const int* src = ei;
    const int* dst = ei + N_EDGES;

    char* ws = (char*)d_ws;
    auto alignup = [](size_t v) { return (v + 255) & ~(size_t)255; };
    int*   bcnt  = (int*)ws;                       ws += alignup((size_t)NBUCK * 16 * 4);
    int*   bbase = (int*)ws;                       ws += alignup((size_t)(NBUCK + 1) * 4);
    int*   off   = (int*)ws;                       ws += alignup((size_t)(N_NODES + 1) * 4);
    int*   esrc  = (int*)ws;                       ws += alignup((size_t)N_EDGES * 4);
    unsigned short* h1b = (unsigned short*)ws;     ws += alignup((size_t)N_NODES * HID * 2);
    // bbuf and h2 share a slab: bbuf dead before l2_mfma writes h2
    int2*  bbuf  = (int2*)ws;
    float* h2    = (float*)ws;

    hipMemsetAsync(bcnt, 0, (size_t)NBUCK * 16 * 4, stream);

    bucketA<<<NBLKA, BLKA, 0, stream>>>(src, dst, bcnt, bbuf);
    scanBuck<<<1, 256, 0, stream>>>(bcnt, bbase, off);
    bucketB<<<NBUCK, 1024, 0, stream>>>(bbuf, bcnt, bbase, off, esrc);

    l1_mfma<<<NBLK2, BLK2, 0, stream>>>(x, off, esrc, W1a, b1a, W1b, b1b, h1b);
    l2_mfma<<<NBLK2, BLK2, 0, stream>>>((const unsigned*)h1b, off, esrc, W2a, b2a, W2b, b2b, h2);
    pool<<<N_GRAPHS, 256, 0, stream>>>(h2, bat, out);
}

// Round 10
// 153.703 us; speedup vs baseline: 5.0606x; 1.2384x over previous
//
#include <hip/hip_runtime.h>
#include <hip/hip_bf16.h>

#define N_NODES  100000
#define N_EDGES  1600000
#define N_GRAPHS 128
#define HID      64
#define NBUCK    256
#define NPB      391                 // nodes per bucket: ceil(100000/256)
#define CAP      8192                // per-bucket record capacity (mean 6250)
#define BLKA     1024
#define EPTA     4
#define EPBA     (BLKA * EPTA)       // 4096 edges per pass-A block
#define NBLKA    ((N_EDGES + EPBA - 1) / EPBA)   // 391

#define NTILES   (N_NODES / 16)      // 6250 (exact)
#define BLK2     512
#define WPB2     (BLK2 / 64)         // 8 waves per block
#define NBLK2    1024                // 8192 waves
#define NWAVES2  (NBLK2 * WPB2)      // 8192
#define TCW      256                 // per-tile fixed-cost weight for balancing
#define PCHUNK   16                  // pool chunks per graph

typedef short short8v __attribute__((ext_vector_type(8)));
typedef float float4v __attribute__((ext_vector_type(4)));

__device__ __forceinline__ float bl_lo(unsigned u) { return __uint_as_float(u << 16); }
__device__ __forceinline__ float bl_hi(unsigned u) { return __uint_as_float(u & 0xffff0000u); }
__device__ __forceinline__ unsigned short f2bf(float f) {
    unsigned u = __float_as_uint(f);
    u += 0x7fffu + ((u >> 16) & 1u);           // round-to-nearest-even
    return (unsigned short)(u >> 16);
}

// ---------------- Pass A: block-local LDS counting sort into 256 dst-range buckets ----------------
__global__ __launch_bounds__(1024) void bucketA(const int* __restrict__ src,
                                                const int* __restrict__ dst,
                                                int* __restrict__ bcnt,      // [NBUCK*16], line-padded
                                                int2* __restrict__ bbuf) {   // [NBUCK*CAP]
    __shared__ int cnt[NBUCK], scn[NBUCK], cur[NBUCK], gb[NBUCK];
    __shared__ int2 srt[EPBA];                    // 32 KB
    int tid = threadIdx.x;
    if (tid < NBUCK) cnt[tid] = 0;
    __syncthreads();

    int e0 = (blockIdx.x * BLKA + tid) * EPTA;
    int s[EPTA], d[EPTA], b[EPTA];
    int nv = 0;
    if (e0 + EPTA <= N_EDGES) {
        int4 s4 = *reinterpret_cast<const int4*>(src + e0);
        int4 d4 = *reinterpret_cast<const int4*>(dst + e0);
        s[0] = s4.x; s[1] = s4.y; s[2] = s4.z; s[3] = s4.w;
        d[0] = d4.x; d[1] = d4.y; d[2] = d4.z; d[3] = d4.w;
        nv = EPTA;
    } else {
        for (int e = e0; e < N_EDGES; ++e) { s[nv] = src[e]; d[nv] = dst[e]; ++nv; }
    }
    for (int k = 0; k < nv; ++k) {
        b[k] = (int)((unsigned)d[k] / (unsigned)NPB);
        atomicAdd(&cnt[b[k]], 1);
    }
    __syncthreads();

    if (tid < NBUCK) scn[tid] = cnt[tid];
    __syncthreads();
    for (int o = 1; o < NBUCK; o <<= 1) {
        int v = 0;
        if (tid < NBUCK && tid >= o) v = scn[tid - o];
        __syncthreads();
        if (tid < NBUCK && tid >= o) scn[tid] += v;
        __syncthreads();
    }
    if (tid < NBUCK) {
        int ex = scn[tid] - cnt[tid];
        cur[tid] = ex;
        gb[tid] = (cnt[tid] > 0) ? atomicAdd(&bcnt[tid * 16], cnt[tid]) : 0;
        scn[tid] = ex;
    }
    __syncthreads();

    for (int k = 0; k < nv; ++k) {
        int p = atomicAdd(&cur[b[k]], 1);
        srt[p] = make_int2(s[k], d[k]);
    }
    __syncthreads();

    int tot = scn[NBUCK - 1] + cnt[NBUCK - 1];
    for (int i = tid; i < tot; i += BLKA) {
        int2 r = srt[i];
        int bb = (int)((unsigned)r.y / (unsigned)NPB);
        bbuf[(size_t)bb * CAP + gb[bb] + (i - scn[bb])] = r;
    }
}

// ---------------- bucket base scan ----------------
__global__ __launch_bounds__(256) void scanBuck(const int* __restrict__ bcnt,
                                                int* __restrict__ bbase,
                                                int* __restrict__ off) {
    __shared__ int s[NBUCK];
    int t = threadIdx.x;
    int own = bcnt[t * 16];
    s[t] = own;
    __syncthreads();
    for (int o = 1; o < NBUCK; o <<= 1) {
        int v = (t >= o) ? s[t - o] : 0;
        __syncthreads();
        s[t] += v;
        __syncthreads();
    }
    bbase[t] = s[t] - own;
    if (t == NBUCK - 1) {
        bbase[NBUCK] = s[t];
        off[N_NODES] = s[t];
    }
}

// ---------------- Pass B: per-bucket CSR via LDS histogram + scan ----------------
__global__ __launch_bounds__(1024) void bucketB(const int2* __restrict__ bbuf,
                                                const int* __restrict__ bcnt,
                                                const int* __restrict__ bbase,
                                                int* __restrict__ off,
                                                int* __restrict__ esrc) {
    __shared__ int hist[NPB], scn[NPB], cur[NPB];
    int b = blockIdx.x, tid = threadIdx.x;
    int node0 = b * NPB;
    int ncnt = N_NODES - node0; if (ncnt > NPB) ncnt = NPB;
    if (tid < ncnt) hist[tid] = 0;
    __syncthreads();

    int cnt  = bcnt[b * 16];
    int base = bbase[b];
    const int2* buf = bbuf + (size_t)b * CAP;

    for (int i = tid; i < cnt; i += 1024)
        atomicAdd(&hist[buf[i].y - node0], 1);
    __syncthreads();

    if (tid < ncnt) scn[tid] = hist[tid];
    __syncthreads();
    for (int o = 1; o < NPB; o <<= 1) {
        int v = 0;
        if (tid < ncnt && tid >= o) v = scn[tid - o];
        __syncthreads();
        if (tid < ncnt && tid >= o) scn[tid] += v;
        __syncthreads();
    }
    if (tid < ncnt) {
        int ex = scn[tid] - hist[tid];
        off[node0 + tid] = base + ex;
        cur[tid] = ex;
    }
    __syncthreads();

    for (int i = tid; i < cnt; i += 1024) {
        int2 r = buf[i];
        int p = atomicAdd(&cur[r.y - node0], 1);
        esrc[base + p] = r.x;
    }
}

// ---------------- balanced tile partition: smallest t with off[16t]+TCW*t >= target ----------------
__device__ __forceinline__ int tile_bound(const int* __restrict__ off, long long target) {
    int lo = 0, hi = NTILES;
    while (lo < hi) {
        int mid = (lo + hi) >> 1;
        long long v = (long long)off[mid * 16] + (long long)TCW * mid;
        if (v < target) lo = mid + 1; else hi = mid;
    }
    return lo;
}

// ---------------- Layer 1: parallel gather(x) + scalar layer-a + MFMA layer-b -> h1 (bf16) ----------------
__global__ __launch_bounds__(512, 8) void l1_mfma(const float* __restrict__ x,
                                                  const int* __restrict__ off,
                                                  const int* __restrict__ esrc,
                                                  const float* __restrict__ W1a,
                                                  const float* __restrict__ b1a,
                                                  const float* __restrict__ W1b,
                                                  const float* __restrict__ b1b,
                                                  unsigned short* __restrict__ h1b) {
    __shared__ float sWa[3 * 64];
    __shared__ float sba[64], sbb[64];
    __shared__ __align__(16) unsigned short sWbT[64 * 72];   // sWbT[n*72+k] = bf16(W1b[k][n])
    __shared__ __align__(16) unsigned short stA[WPB2][16][72];

    int tid = threadIdx.x;
    for (int i = tid; i < 3 * 64; i += BLK2) sWa[i] = W1a[i];
    for (int i = tid; i < 64 * 64; i += BLK2) {
        int k = i >> 6, n = i & 63;
        sWbT[n * 72 + k] = f2bf(W1b[i]);
    }
    if (tid < 64) { sba[tid] = b1a[tid]; sbb[tid] = b1b[tid]; }
    __syncthreads();

    int w = tid >> 6;
    int l = tid & 63;
    int c  = l & 3;           // component 0..2 (lane c==3 contributes 0)
    int cc = (c < 3) ? c : 0;
    int ei = l >> 2;          // edge slot 0..15
    int m  = l & 15;          // A row / D col
    int kg = l >> 4;          // k-group / D row-group
    int wid = blockIdx.x * WPB2 + w;

    const long long TOT = (long long)N_EDGES + (long long)TCW * NTILES;
    int t0 = tile_bound(off, TOT * wid / NWAVES2);
    int t1 = tile_bound(off, TOT * (wid + 1) / NWAVES2);

    for (int t = t0; t < t1; ++t) {
        int nt0 = t * 16;
        for (int mm = 0; mm < 16; ++mm) {
            int n = nt0 + mm;
            int start = off[n], end = off[n + 1];
            float a = 0.f;
            for (int eb = start; eb < end; eb += 16) {
                int e = eb + ei;
                int es = e < end ? e : end - 1;
                int s = esrc[es];
                float v = x[s * 3 + cc];
                if (c == 3 || e >= end) v = 0.f;
                a += v;
            }
#pragma unroll
            for (int d = 4; d < 64; d <<= 1) a += __shfl_xor(a, d);
            float in0 = __shfl(a, 0) + x[n * 3 + 0];
            float in1 = __shfl(a, 1) + x[n * 3 + 1];
            float in2 = __shfl(a, 2) + x[n * 3 + 2];
            float tt = sba[l] + in0 * sWa[l] + in1 * sWa[64 + l] + in2 * sWa[128 + l];
            stA[w][mm][l] = f2bf(fmaxf(tt, 0.0f));
        }
        __builtin_amdgcn_wave_barrier();

        short8v A0 = *reinterpret_cast<const short8v*>(&stA[w][m][kg * 8]);
        short8v A1 = *reinterpret_cast<const short8v*>(&stA[w][m][32 + kg * 8]);
#pragma unroll
        for (int cq = 0; cq < 4; ++cq) {
            short8v B0 = *reinterpret_cast<const short8v*>(&sWbT[(16 * cq + m) * 72 + kg * 8]);
            short8v B1 = *reinterpret_cast<const short8v*>(&sWbT[(16 * cq + m) * 72 + 32 + kg * 8]);
            float bb = sbb[16 * cq + m];
            float4v acc = {bb, bb, bb, bb};
            acc = __builtin_amdgcn_mfma_f32_16x16x32_bf16(A0, B0, acc, 0, 0, 0);
            acc = __builtin_amdgcn_mfma_f32_16x16x32_bf16(A1, B1, acc, 0, 0, 0);
#pragma unroll
            for (int i = 0; i < 4; ++i)
                h1b[(size_t)(nt0 + kg * 4 + i) * 64 + 16 * cq + m] = f2bf(fmaxf(acc[i], 0.0f));
        }
        __builtin_amdgcn_wave_barrier();
    }
}

// ---------------- Layer 2: deep-unrolled bf16 gather + double MFMA MLP -> h2 (f32) ----------------
__global__ __launch_bounds__(512, 8) void l2_mfma(const unsigned* __restrict__ h1p,   // packed 2xbf16
                                                  const int* __restrict__ off,
                                                  const int* __restrict__ esrc,
                                                  const float* __restrict__ W2a,
                                                  const float* __restrict__ b2a,
                                                  const float* __restrict__ W2b,
                                                  const float* __restrict__ b2b,
                                                  float* __restrict__ h2) {
    __shared__ float sba[64], sbb[64];
    __shared__ __align__(16) unsigned short sWaT[64 * 72];   // sWaT[n*72+k] = bf16(W2a[k][n])
    __shared__ __align__(16) unsigned short sWbT[64 * 72];
    __shared__ __align__(16) unsigned short stA[WPB2][16][72];

    int tid = threadIdx.x;
    for (int i = tid; i < 64 * 64; i += BLK2) {
        int k = i >> 6, n = i & 63;
        sWaT[n * 72 + k] = f2bf(W2a[i]);
        sWbT[n * 72 + k] = f2bf(W2b[i]);
    }
    if (tid < 64) { sba[tid] = b2a[tid]; sbb[tid] = b2b[tid]; }
    __syncthreads();

    int w = tid >> 6;
    int l = tid & 63;
    int g = l >> 4;          // edge slot 0..3
    int q = l & 15;          // 8B chunk of 128B row
    int m  = l & 15;
    int kg = l >> 4;
    int wid = blockIdx.x * WPB2 + w;

    const long long TOT = (long long)N_EDGES + (long long)TCW * NTILES;
    int t0 = tile_bound(off, TOT * wid / NWAVES2);
    int t1 = tile_bound(off, TOT * (wid + 1) / NWAVES2);

    for (int t = t0; t < t1; ++t) {
        int nt0 = t * 16;
        // ---- gather 16 nodes -> stA rows (bf16) ----
        for (int mm = 0; mm < 16; ++mm) {
            int n = nt0 + mm;
            int start = off[n], end = off[n + 1];
            float a0 = 0.f, a1 = 0.f, a2 = 0.f, a3 = 0.f;
            if (g == 0) {      // self term once
                uint2 v = *reinterpret_cast<const uint2*>(h1p + (size_t)n * 32 + 2 * q);
                a0 += bl_lo(v.x); a1 += bl_hi(v.x); a2 += bl_lo(v.y); a3 += bl_hi(v.y);
            }
            for (int e = start; e < end; e += 16) {
                int tA = e + g, tB = e + 4 + g, tC = e + 8 + g, tD = e + 12 + g;
                int iA = tA < end ? tA : end - 1;
                int iB = tB < end ? tB : end - 1;
                int iC = tC < end ? tC : end - 1;
                int iD = tD < end ? tD : end - 1;
                int sA = esrc[iA], sB = esrc[iB], sC = esrc[iC], sD = esrc[iD];
                uint2 vA = *reinterpret_cast<const uint2*>(h1p + (size_t)sA * 32 + 2 * q);
                uint2 vB = *reinterpret_cast<const uint2*>(h1p + (size_t)sB * 32 + 2 * q);
                uint2 vC = *reinterpret_cast<const uint2*>(h1p + (size_t)sC * 32 + 2 * q);
                uint2 vD = *reinterpret_cast<const uint2*>(h1p + (size_t)sD * 32 + 2 * q);
                unsigned mA = tA < end ? 0xffffffffu : 0u;
                unsigned mB = tB < end ? 0xffffffffu : 0u;
                unsigned mC = tC < end ? 0xffffffffu : 0u;
                unsigned mD = tD < end ? 0xffffffffu : 0u;
                a0 += (bl_lo(vA.x & mA) + bl_lo(vB.x & mB)) + (bl_lo(vC.x & mC) + bl_lo(vD.x & mD));
                a1 += (bl_hi(vA.x & mA) + bl_hi(vB.x & mB)) + (bl_hi(vC.x & mC) + bl_hi(vD.x & mD));
                a2 += (bl_lo(vA.y & mA) + bl_lo(vB.y & mB)) + (bl_lo(vC.y & mC) + bl_lo(vD.y & mD));
                a3 += (bl_hi(vA.y & mA) + bl_hi(vB.y & mB)) + (bl_hi(vC.y & mC) + bl_hi(vD.y & mD));
            }
            a0 += __shfl_xor(a0, 16); a0 += __shfl_xor(a0, 32);
            a1 += __shfl_xor(a1, 16); a1 += __shfl_xor(a1, 32);
            a2 += __shfl_xor(a2, 16); a2 += __shfl_xor(a2, 32);
            a3 += __shfl_xor(a3, 16); a3 += __shfl_xor(a3, 32);
            if (g == 0) {
                uint2 pk;
                pk.x = ((unsigned)f2bf(a1) << 16) | (unsigned)f2bf(a0);
                pk.y = ((unsigned)f2bf(a3) << 16) | (unsigned)f2bf(a2);
                *reinterpret_cast<uint2*>(&stA[w][mm][4 * q]) = pk;
            }
        }
        __builtin_amdgcn_wave_barrier();

        // ---- matmul1: relu(agg @ W2a + b2a), restage as bf16 ----
        short8v A0 = *reinterpret_cast<const short8v*>(&stA[w][m][kg * 8]);
        short8v A1 = *reinterpret_cast<const short8v*>(&stA[w][m][32 + kg * 8]);
#pragma unroll
        for (int cq = 0; cq < 4; ++cq) {
            short8v B0 = *reinterpret_cast<const short8v*>(&sWaT[(16 * cq + m) * 72 + kg * 8]);
            short8v B1 = *reinterpret_cast<const short8v*>(&sWaT[(16 * cq + m) * 72 + 32 + kg * 8]);
            float bb = sba[16 * cq + m];
            float4v acc = {bb, bb, bb, bb};
            acc = __builtin_amdgcn_mfma_f32_16x16x32_bf16(A0, B0, acc, 0, 0, 0);
            acc = __builtin_amdgcn_mfma_f32_16x16x32_bf16(A1, B1, acc, 0, 0, 0);
#pragma unroll
            for (int i = 0; i < 4; ++i)
                stA[w][kg * 4 + i][16 * cq + m] = f2bf(fmaxf(acc[i], 0.0f));
        }
        __builtin_amdgcn_wave_barrier();

        // ---- matmul2: relu(h @ W2b + b2b) -> h2 ----
        short8v C0 = *reinterpret_cast<const short8v*>(&stA[w][m][kg * 8]);
        short8v C1 = *reinterpret_cast<const short8v*>(&stA[w][m][32 + kg * 8]);
#pragma unroll
        for (int cq = 0; cq < 4; ++cq) {
            short8v B0 = *reinterpret_cast<const short8v*>(&sWbT[(16 * cq + m) * 72 + kg * 8]);
            short8v B1 = *reinterpret_cast<const short8v*>(&sWbT[(16 * cq + m) * 72 + 32 + kg * 8]);
            float bb = sbb[16 * cq + m];
            float4v acc = {bb, bb, bb, bb};
            acc = __builtin_amdgcn_mfma_f32_16x16x32_bf16(C0, B0, acc, 0, 0, 0);
            acc = __builtin_amdgcn_mfma_f32_16x16x32_bf16(C1, B1, acc, 0, 0, 0);
#pragma unroll
            for (int i = 0; i < 4; ++i)
                h2[(size_t)(nt0 + kg * 4 + i) * 64 + 16 * cq + m] = fmaxf(acc[i], 0.0f);
        }
        __builtin_amdgcn_wave_barrier();
    }
}

// ---------------- Pool stage A: per-(graph, chunk) partial sums ----------------
__global__ __launch_bounds__(256) void poolA(const float* __restrict__ h2,
                                             const int* __restrict__ batch,
                                             float* __restrict__ partial) {  // [PCHUNK][N_GRAPHS][64]
    int g = blockIdx.x & (N_GRAPHS - 1);
    int c = blockIdx.x >> 7;

    int lo = 0, hi = N_NODES;
    while (lo < hi) { int mid = (lo + hi) >> 1; if (batch[mid] < g) lo = mid + 1; else hi = mid; }
    int start = lo;
    lo = start; hi = N_NODES;
    while (lo < hi) { int mid = (lo + hi) >> 1; if (batch[mid] < g + 1) lo = mid + 1; else hi = mid; }
    int end = lo;

    int len = end - start;
    int cs = start + (int)((long long)len * c / PCHUNK);
    int ce = start + (int)((long long)len * (c + 1) / PCHUNK);

    int j = threadIdx.x & 63;
    int r = threadIdx.x >> 6;
    float local = 0.0f;
    for (int n = cs + r; n < ce; n += 4)
        local += h2[(size_t)n * 64 + j];

    __shared__ float red[4][64];
    red[r][j] = local;
    __syncthreads();
    if (r == 0)
        partial[((size_t)c * N_GRAPHS + g) * 64 + j] = red[0][j] + red[1][j] + red[2][j] + red[3][j];
}

// ---------------- Pool stage B: reduce chunks, divide by count ----------------
__global__ __launch_bounds__(64) void poolB(const float* __restrict__ partial,
                                            const int* __restrict__ batch,
                                            float* __restrict__ out) {
    int g = blockIdx.x;
    int j = threadIdx.x;

    int lo = 0, hi = N_NODES;
    while (lo < hi) { int mid = (lo + hi) >> 1; if (batch[mid] < g) lo = mid + 1; else hi = mid; }
    int start = lo;
    lo = start; hi = N_NODES;
    while (lo < hi) { int mid = (lo + hi) >> 1; if (batch[mid] < g + 1) lo = mid + 1; else hi = mid; }
    int end = lo;

    float s = 0.0f;
#pragma unroll
    for (int c = 0; c < PCHUNK; ++c)
        s += partial[((size_t)c * N_GRAPHS + g) * 64 + j];
    float cnt = (float)((end - start) > 1 ? (end - start) : 1);
    out[g * 64 + j] = s / cnt;
}

extern "C" void kernel_launch(void* const* d_in, const int* in_sizes, int n_in,
                              void* d_out, int out_size, void* d_ws, size_t ws_size,
                              hipStream_t stream) {
    const float* x    = (const float*)d_in[0];
    const int*   ei   = (const int*)d_in[1];
    const int*   bat  = (const int*)d_in[2];
    const float* W1a  = (const float*)d_in[3];
    const float* b1a  = (const float*)d_in[4];
    const float* W1b  = (const float*)d_in[5];
    const float* b1b  = (const float*)d_in[6];
    const float* W2a  = (const float*)d_in[7];
    const float* b2a  = (const float*)d_in[8];
    const float* W2b  = (const float*)d_in[9];
    const float* b2b  = (const float*)d_in[10];
    float* out = (float*)d_out;

    const int* src = ei;
    const int* dst = ei + N_EDGES;

    char* ws = (char*)d_ws;
    auto alignup = [](size_t v) { return (v + 255) & ~(size_t)255; };
    int*   bcnt  = (int*)ws;                       ws += alignup((size_t)NBUCK * 16 * 4);
    int*   bbase = (int*)ws;                       ws += alignup((size_t)(NBUCK + 1) * 4);
    int*   off   = (int*)ws;                       ws += alignup((size_t)(N_NODES + 1) * 4);
    int*   esrc  = (int*)ws;                       ws += alignup((size_t)N_EDGES * 4);
    unsigned short* h1b = (unsigned short*)ws;     ws += alignup((size_t)N_NODES * HID * 2);
    float* partial = (float*)ws;                   ws += alignup((size_t)PCHUNK * N_GRAPHS * 64 * 4);
    // bbuf and h2 share a slab: bbuf dead before l2_mfma writes h2
    int2*  bbuf  = (int2*)ws;
    float* h2    = (float*)ws;

    hipMemsetAsync(bcnt, 0, (size_t)NBUCK * 16 * 4, stream);

    bucketA<<<NBLKA, BLKA, 0, stream>>>(src, dst, bcnt, bbuf);
    scanBuck<<<1, 256, 0, stream>>>(bcnt, bbase, off);
    bucketB<<<NBUCK, 1024, 0, stream>>>(bbuf, bcnt, bbase, off, esrc);

    l1_mfma<<<NBLK2, BLK2, 0, stream>>>(x, off, esrc, W1a, b1a, W1b, b1b, h1b);
    l2_mfma<<<NBLK2, BLK2, 0, stream>>>((const unsigned*)h1b, off, esrc, W2a, b2a, W2b, b2b, h2);

    poolA<<<N_GRAPHS * PCHUNK, 256, 0, stream>>>(h2, bat, partial);
    poolB<<<N_GRAPHS, 64, 0, stream>>>(partial, bat, out);
}

// Round 11
// 150.561 us; speedup vs baseline: 5.1662x; 1.0209x over previous
//
#include <hip/hip_runtime.h>
#include <hip/hip_bf16.h>

#define N_NODES  100000
#define N_EDGES  1600000
#define N_GRAPHS 128
#define HID      64
#define NBUCK    256
#define NPB      391                 // nodes per bucket: ceil(100000/256)
#define CAP      8192                // per-bucket record capacity (mean 6250)
#define BLKA     1024
#define EPTA     4
#define EPBA     (BLKA * EPTA)       // 4096 edges per pass-A block
#define NBLKA    ((N_EDGES + EPBA - 1) / EPBA)   // 391

#define NTILES   (N_NODES / 16)      // 6250 (exact)
#define BLK2     512
#define WPB2     (BLK2 / 64)         // 8 waves per block
#define NBLK2    1024                // 8192 waves
#define NWAVES2  (NBLK2 * WPB2)      // 8192
#define TCW      256                 // per-tile fixed-cost weight for balancing
#define PCHUNK   16                  // pool chunks per graph

typedef short short8v __attribute__((ext_vector_type(8)));
typedef float float4v __attribute__((ext_vector_type(4)));

__device__ __forceinline__ float bl_lo(unsigned u) { return __uint_as_float(u << 16); }
__device__ __forceinline__ float bl_hi(unsigned u) { return __uint_as_float(u & 0xffff0000u); }
__device__ __forceinline__ unsigned short f2bf(float f) {
    unsigned u = __float_as_uint(f);
    u += 0x7fffu + ((u >> 16) & 1u);           // round-to-nearest-even
    return (unsigned short)(u >> 16);
}

// ---------------- Pass A: block-local LDS counting sort into 256 dst-range buckets ----------------
__global__ __launch_bounds__(1024) void bucketA(const int* __restrict__ src,
                                                const int* __restrict__ dst,
                                                int* __restrict__ bcnt,      // [NBUCK*16], line-padded
                                                int2* __restrict__ bbuf) {   // [NBUCK*CAP]
    __shared__ int cnt[NBUCK], scn[NBUCK], cur[NBUCK], gb[NBUCK];
    __shared__ int2 srt[EPBA];                    // 32 KB
    int tid = threadIdx.x;
    if (tid < NBUCK) cnt[tid] = 0;
    __syncthreads();

    int e0 = (blockIdx.x * BLKA + tid) * EPTA;
    int s[EPTA], d[EPTA], b[EPTA];
    int nv = 0;
    if (e0 + EPTA <= N_EDGES) {
        int4 s4 = *reinterpret_cast<const int4*>(src + e0);
        int4 d4 = *reinterpret_cast<const int4*>(dst + e0);
        s[0] = s4.x; s[1] = s4.y; s[2] = s4.z; s[3] = s4.w;
        d[0] = d4.x; d[1] = d4.y; d[2] = d4.z; d[3] = d4.w;
        nv = EPTA;
    } else {
        for (int e = e0; e < N_EDGES; ++e) { s[nv] = src[e]; d[nv] = dst[e]; ++nv; }
    }
    for (int k = 0; k < nv; ++k) {
        b[k] = (int)((unsigned)d[k] / (unsigned)NPB);
        atomicAdd(&cnt[b[k]], 1);
    }
    __syncthreads();

    if (tid < NBUCK) scn[tid] = cnt[tid];
    __syncthreads();
    for (int o = 1; o < NBUCK; o <<= 1) {
        int v = 0;
        if (tid < NBUCK && tid >= o) v = scn[tid - o];
        __syncthreads();
        if (tid < NBUCK && tid >= o) scn[tid] += v;
        __syncthreads();
    }
    if (tid < NBUCK) {
        int ex = scn[tid] - cnt[tid];
        cur[tid] = ex;
        gb[tid] = (cnt[tid] > 0) ? atomicAdd(&bcnt[tid * 16], cnt[tid]) : 0;
        scn[tid] = ex;
    }
    __syncthreads();

    for (int k = 0; k < nv; ++k) {
        int p = atomicAdd(&cur[b[k]], 1);
        srt[p] = make_int2(s[k], d[k]);
    }
    __syncthreads();

    int tot = scn[NBUCK - 1] + cnt[NBUCK - 1];
    for (int i = tid; i < tot; i += BLKA) {
        int2 r = srt[i];
        int bb = (int)((unsigned)r.y / (unsigned)NPB);
        bbuf[(size_t)bb * CAP + gb[bb] + (i - scn[bb])] = r;
    }
}

// ---------------- bucket base scan ----------------
__global__ __launch_bounds__(256) void scanBuck(const int* __restrict__ bcnt,
                                                int* __restrict__ bbase,
                                                int* __restrict__ off) {
    __shared__ int s[NBUCK];
    int t = threadIdx.x;
    int own = bcnt[t * 16];
    s[t] = own;
    __syncthreads();
    for (int o = 1; o < NBUCK; o <<= 1) {
        int v = (t >= o) ? s[t - o] : 0;
        __syncthreads();
        s[t] += v;
        __syncthreads();
    }
    bbase[t] = s[t] - own;
    if (t == NBUCK - 1) {
        bbase[NBUCK] = s[t];
        off[N_NODES] = s[t];
    }
}

// ---------------- Pass B: per-bucket CSR via LDS histogram + scan ----------------
__global__ __launch_bounds__(1024) void bucketB(const int2* __restrict__ bbuf,
                                                const int* __restrict__ bcnt,
                                                const int* __restrict__ bbase,
                                                int* __restrict__ off,
                                                int* __restrict__ esrc) {
    __shared__ int hist[NPB], scn[NPB], cur[NPB];
    int b = blockIdx.x, tid = threadIdx.x;
    int node0 = b * NPB;
    int ncnt = N_NODES - node0; if (ncnt > NPB) ncnt = NPB;
    if (tid < ncnt) hist[tid] = 0;
    __syncthreads();

    int cnt  = bcnt[b * 16];
    int base = bbase[b];
    const int2* buf = bbuf + (size_t)b * CAP;

    for (int i = tid; i < cnt; i += 1024)
        atomicAdd(&hist[buf[i].y - node0], 1);
    __syncthreads();

    if (tid < ncnt) scn[tid] = hist[tid];
    __syncthreads();
    for (int o = 1; o < NPB; o <<= 1) {
        int v = 0;
        if (tid < ncnt && tid >= o) v = scn[tid - o];
        __syncthreads();
        if (tid < ncnt && tid >= o) scn[tid] += v;
        __syncthreads();
    }
    if (tid < ncnt) {
        int ex = scn[tid] - hist[tid];
        off[node0 + tid] = base + ex;
        cur[tid] = ex;
    }
    __syncthreads();

    for (int i = tid; i < cnt; i += 1024) {
        int2 r = buf[i];
        int p = atomicAdd(&cur[r.y - node0], 1);
        esrc[base + p] = r.x;
    }
}

// ---------------- balanced tile partition: smallest t with off[16t]+TCW*t >= target ----------------
__device__ __forceinline__ int tile_bound(const int* __restrict__ off, long long target) {
    int lo = 0, hi = NTILES;
    while (lo < hi) {
        int mid = (lo + hi) >> 1;
        long long v = (long long)off[mid * 16] + (long long)TCW * mid;
        if (v < target) lo = mid + 1; else hi = mid;
    }
    return lo;
}

// ---------------- Layer 1: paired-node gather(x) + scalar layer-a + MFMA layer-b -> h1 (bf16) ----------------
__global__ __launch_bounds__(512, 8) void l1_mfma(const float* __restrict__ x,
                                                  const int* __restrict__ off,
                                                  const int* __restrict__ esrc,
                                                  const float* __restrict__ W1a,
                                                  const float* __restrict__ b1a,
                                                  const float* __restrict__ W1b,
                                                  const float* __restrict__ b1b,
                                                  unsigned short* __restrict__ h1b) {
    __shared__ float sWa[3 * 64];
    __shared__ float sba[64], sbb[64];
    __shared__ __align__(16) unsigned short sWbT[64 * 72];   // sWbT[n*72+k] = bf16(W1b[k][n])
    __shared__ __align__(16) unsigned short stA[WPB2][16][72];

    int tid = threadIdx.x;
    for (int i = tid; i < 3 * 64; i += BLK2) sWa[i] = W1a[i];
    for (int i = tid; i < 64 * 64; i += BLK2) {
        int k = i >> 6, n = i & 63;
        sWbT[n * 72 + k] = f2bf(W1b[i]);
    }
    if (tid < 64) { sba[tid] = b1a[tid]; sbb[tid] = b1b[tid]; }
    __syncthreads();

    int w = tid >> 6;
    int l = tid & 63;
    int c  = l & 3;           // component 0..2 (lane c==3 contributes 0)
    int cc = (c < 3) ? c : 0;
    int ei = l >> 2;          // edge slot 0..15
    int m  = l & 15;          // A row / D col
    int kg = l >> 4;          // k-group / D row-group
    int wid = blockIdx.x * WPB2 + w;

    const long long TOT = (long long)N_EDGES + (long long)TCW * NTILES;
    int t0 = tile_bound(off, TOT * wid / NWAVES2);
    int t1 = tile_bound(off, TOT * (wid + 1) / NWAVES2);

    for (int t = t0; t < t1; ++t) {
        int nt0 = t * 16;
        for (int mm = 0; mm < 8; ++mm) {
            int n0 = nt0 + mm, n1 = nt0 + mm + 8;
            int sA = off[n0], eA = off[n0 + 1];
            int sB = off[n1], eB = off[n1 + 1];
            int emA = max(eA - 1, 0);
            int emB = max(eB - 1, 0);
            float a = 0.f, b = 0.f;
            int e0 = sA, e1 = sB;
            while (e0 < eA || e1 < eB) {
                int ea_ = e0 + ei;
                int eb_ = e1 + ei;
                int ia = min(ea_, emA);
                int ib = min(eb_, emB);
                int sa = esrc[ia];
                int sb = esrc[ib];
                float va = x[sa * 3 + cc];
                float vb = x[sb * 3 + cc];
                if (c == 3 || ea_ >= eA) va = 0.f;
                if (c == 3 || eb_ >= eB) vb = 0.f;
                a += va; b += vb;
                e0 += 16; e1 += 16;
            }
#pragma unroll
            for (int d = 4; d < 64; d <<= 1) {
                a += __shfl_xor(a, d);
                b += __shfl_xor(b, d);
            }
            float i00 = __shfl(a, 0) + x[n0 * 3 + 0];
            float i01 = __shfl(a, 1) + x[n0 * 3 + 1];
            float i02 = __shfl(a, 2) + x[n0 * 3 + 2];
            float i10 = __shfl(b, 0) + x[n1 * 3 + 0];
            float i11 = __shfl(b, 1) + x[n1 * 3 + 1];
            float i12 = __shfl(b, 2) + x[n1 * 3 + 2];
            float t0v = sba[l] + i00 * sWa[l] + i01 * sWa[64 + l] + i02 * sWa[128 + l];
            float t1v = sba[l] + i10 * sWa[l] + i11 * sWa[64 + l] + i12 * sWa[128 + l];
            stA[w][mm][l]     = f2bf(fmaxf(t0v, 0.0f));
            stA[w][mm + 8][l] = f2bf(fmaxf(t1v, 0.0f));
        }
        __builtin_amdgcn_wave_barrier();

        short8v A0 = *reinterpret_cast<const short8v*>(&stA[w][m][kg * 8]);
        short8v A1 = *reinterpret_cast<const short8v*>(&stA[w][m][32 + kg * 8]);
#pragma unroll
        for (int cq = 0; cq < 4; ++cq) {
            short8v B0 = *reinterpret_cast<const short8v*>(&sWbT[(16 * cq + m) * 72 + kg * 8]);
            short8v B1 = *reinterpret_cast<const short8v*>(&sWbT[(16 * cq + m) * 72 + 32 + kg * 8]);
            float bb = sbb[16 * cq + m];
            float4v acc = {bb, bb, bb, bb};
            acc = __builtin_amdgcn_mfma_f32_16x16x32_bf16(A0, B0, acc, 0, 0, 0);
            acc = __builtin_amdgcn_mfma_f32_16x16x32_bf16(A1, B1, acc, 0, 0, 0);
#pragma unroll
            for (int i = 0; i < 4; ++i)
                h1b[(size_t)(nt0 + kg * 4 + i) * 64 + 16 * cq + m] = f2bf(fmaxf(acc[i], 0.0f));
        }
        __builtin_amdgcn_wave_barrier();
    }
}

// ---------------- Layer 2: paired-node bf16 gather + double MFMA MLP -> h2 (f32) ----------------
__global__ __launch_bounds__(512, 8) void l2_mfma(const unsigned* __restrict__ h1p,   // packed 2xbf16
                                                  const int* __restrict__ off,
                                                  const int* __restrict__ esrc,
                                                  const float* __restrict__ W2a,
                                                  const float* __restrict__ b2a,
                                                  const float* __restrict__ W2b,
                                                  const float* __restrict__ b2b,
                                                  float* __restrict__ h2) {
    __shared__ float sba[64], sbb[64];
    __shared__ __align__(16) unsigned short sWaT[64 * 72];   // sWaT[n*72+k] = bf16(W2a[k][n])
    __shared__ __align__(16) unsigned short sWbT[64 * 72];
    __shared__ __align__(16) unsigned short stA[WPB2][16][72];

    int tid = threadIdx.x;
    for (int i = tid; i < 64 * 64; i += BLK2) {
        int k = i >> 6, n = i & 63;
        sWaT[n * 72 + k] = f2bf(W2a[i]);
        sWbT[n * 72 + k] = f2bf(W2b[i]);
    }
    if (tid < 64) { sba[tid] = b2a[tid]; sbb[tid] = b2b[tid]; }
    __syncthreads();

    int w = tid >> 6;
    int l = tid & 63;
    int g = l >> 4;          // edge slot 0..3
    int q = l & 15;          // 8B chunk of 128B row
    int m  = l & 15;
    int kg = l >> 4;
    int wid = blockIdx.x * WPB2 + w;

    const long long TOT = (long long)N_EDGES + (long long)TCW * NTILES;
    int t0 = tile_bound(off, TOT * wid / NWAVES2);
    int t1 = tile_bound(off, TOT * (wid + 1) / NWAVES2);

    for (int t = t0; t < t1; ++t) {
        int nt0 = t * 16;
        // ---- paired gather: nodes (mm, mm+8) interleaved for 2x loads in flight ----
        for (int mm = 0; mm < 8; ++mm) {
            int n0 = nt0 + mm, n1 = nt0 + mm + 8;
            int sA = off[n0], eA = off[n0 + 1];
            int sB = off[n1], eB = off[n1 + 1];
            int emA = max(eA - 1, 0);
            int emB = max(eB - 1, 0);
            float a0 = 0.f, a1 = 0.f, a2 = 0.f, a3 = 0.f;   // node0
            float b0 = 0.f, b1 = 0.f, b2 = 0.f, b3 = 0.f;   // node1
            if (g == 0) {      // self terms once
                uint2 v0 = *reinterpret_cast<const uint2*>(h1p + (size_t)n0 * 32 + 2 * q);
                uint2 v1 = *reinterpret_cast<const uint2*>(h1p + (size_t)n1 * 32 + 2 * q);
                a0 += bl_lo(v0.x); a1 += bl_hi(v0.x); a2 += bl_lo(v0.y); a3 += bl_hi(v0.y);
                b0 += bl_lo(v1.x); b1 += bl_hi(v1.x); b2 += bl_lo(v1.y); b3 += bl_hi(v1.y);
            }
            int e0 = sA, e1 = sB;
            while (e0 < eA || e1 < eB) {
                int tA = e0 + g,     tB = e0 + 4 + g, tC = e0 + 8 + g,  tD = e0 + 12 + g;
                int tE = e1 + g,     tF = e1 + 4 + g, tG = e1 + 8 + g,  tH = e1 + 12 + g;
                int iA = min(tA, emA), iB = min(tB, emA), iC = min(tC, emA), iD = min(tD, emA);
                int iE = min(tE, emB), iF = min(tF, emB), iG = min(tG, emB), iH = min(tH, emB);
                int sa = esrc[iA], sb = esrc[iB], sc = esrc[iC], sd = esrc[iD];
                int se = esrc[iE], sf = esrc[iF], sg = esrc[iG], sh = esrc[iH];
                uint2 vA = *reinterpret_cast<const uint2*>(h1p + (size_t)sa * 32 + 2 * q);
                uint2 vB = *reinterpret_cast<const uint2*>(h1p + (size_t)sb * 32 + 2 * q);
                uint2 vC = *reinterpret_cast<const uint2*>(h1p + (size_t)sc * 32 + 2 * q);
                uint2 vD = *reinterpret_cast<const uint2*>(h1p + (size_t)sd * 32 + 2 * q);
                uint2 vE = *reinterpret_cast<const uint2*>(h1p + (size_t)se * 32 + 2 * q);
                uint2 vF = *reinterpret_cast<const uint2*>(h1p + (size_t)sf * 32 + 2 * q);
                uint2 vG = *reinterpret_cast<const uint2*>(h1p + (size_t)sg * 32 + 2 * q);
                uint2 vH = *reinterpret_cast<const uint2*>(h1p + (size_t)sh * 32 + 2 * q);
                unsigned mA = tA < eA ? 0xffffffffu : 0u;
                unsigned mB = tB < eA ? 0xffffffffu : 0u;
                unsigned mC = tC < eA ? 0xffffffffu : 0u;
                unsigned mD = tD < eA ? 0xffffffffu : 0u;
                unsigned mE = tE < eB ? 0xffffffffu : 0u;
                unsigned mF = tF < eB ? 0xffffffffu : 0u;
                unsigned mG = tG < eB ? 0xffffffffu : 0u;
                unsigned mH = tH < eB ? 0xffffffffu : 0u;
                a0 += (bl_lo(vA.x & mA) + bl_lo(vB.x & mB)) + (bl_lo(vC.x & mC) + bl_lo(vD.x & mD));
                a1 += (bl_hi(vA.x & mA) + bl_hi(vB.x & mB)) + (bl_hi(vC.x & mC) + bl_hi(vD.x & mD));
                a2 += (bl_lo(vA.y & mA) + bl_lo(vB.y & mB)) + (bl_lo(vC.y & mC) + bl_lo(vD.y & mD));
                a3 += (bl_hi(vA.y & mA) + bl_hi(vB.y & mB)) + (bl_hi(vC.y & mC) + bl_hi(vD.y & mD));
                b0 += (bl_lo(vE.x & mE) + bl_lo(vF.x & mF)) + (bl_lo(vG.x & mG) + bl_lo(vH.x & mH));
                b1 += (bl_hi(vE.x & mE) + bl_hi(vF.x & mF)) + (bl_hi(vG.x & mG) + bl_hi(vH.x & mH));
                b2 += (bl_lo(vE.y & mE) + bl_lo(vF.y & mF)) + (bl_lo(vG.y & mG) + bl_lo(vH.y & mH));
                b3 += (bl_hi(vE.y & mE) + bl_hi(vF.y & mF)) + (bl_hi(vG.y & mG) + bl_hi(vH.y & mH));
                e0 += 16; e1 += 16;
            }
            a0 += __shfl_xor(a0, 16); a0 += __shfl_xor(a0, 32);
            a1 += __shfl_xor(a1, 16); a1 += __shfl_xor(a1, 32);
            a2 += __shfl_xor(a2, 16); a2 += __shfl_xor(a2, 32);
            a3 += __shfl_xor(a3, 16); a3 += __shfl_xor(a3, 32);
            b0 += __shfl_xor(b0, 16); b0 += __shfl_xor(b0, 32);
            b1 += __shfl_xor(b1, 16); b1 += __shfl_xor(b1, 32);
            b2 += __shfl_xor(b2, 16); b2 += __shfl_xor(b2, 32);
            b3 += __shfl_xor(b3, 16); b3 += __shfl_xor(b3, 32);
            if (g == 0) {
                uint2 pk0, pk1;
                pk0.x = ((unsigned)f2bf(a1) << 16) | (unsigned)f2bf(a0);
                pk0.y = ((unsigned)f2bf(a3) << 16) | (unsigned)f2bf(a2);
                pk1.x = ((unsigned)f2bf(b1) << 16) | (unsigned)f2bf(b0);
                pk1.y = ((unsigned)f2bf(b3) << 16) | (unsigned)f2bf(b2);
                *reinterpret_cast<uint2*>(&stA[w][mm][4 * q])     = pk0;
                *reinterpret_cast<uint2*>(&stA[w][mm + 8][4 * q]) = pk1;
            }
        }
        __builtin_amdgcn_wave_barrier();

        // ---- matmul1: relu(agg @ W2a + b2a), restage as bf16 ----
        short8v A0 = *reinterpret_cast<const short8v*>(&stA[w][m][kg * 8]);
        short8v A1 = *reinterpret_cast<const short8v*>(&stA[w][m][32 + kg * 8]);
#pragma unroll
        for (int cq = 0; cq < 4; ++cq) {
            short8v B0 = *reinterpret_cast<const short8v*>(&sWaT[(16 * cq + m) * 72 + kg * 8]);
            short8v B1 = *reinterpret_cast<const short8v*>(&sWaT[(16 * cq + m) * 72 + 32 + kg * 8]);
            float bb = sba[16 * cq + m];
            float4v acc = {bb, bb, bb, bb};
            acc = __builtin_amdgcn_mfma_f32_16x16x32_bf16(A0, B0, acc, 0, 0, 0);
            acc = __builtin_amdgcn_mfma_f32_16x16x32_bf16(A1, B1, acc, 0, 0, 0);
#pragma unroll
            for (int i = 0; i < 4; ++i)
                stA[w][kg * 4 + i][16 * cq + m] = f2bf(fmaxf(acc[i], 0.0f));
        }
        __builtin_amdgcn_wave_barrier();

        // ---- matmul2: relu(h @ W2b + b2b) -> h2 ----
        short8v C0 = *reinterpret_cast<const short8v*>(&stA[w][m][kg * 8]);
        short8v C1 = *reinterpret_cast<const short8v*>(&stA[w][m][32 + kg * 8]);
#pragma unroll
        for (int cq = 0; cq < 4; ++cq) {
            short8v B0 = *reinterpret_cast<const short8v*>(&sWbT[(16 * cq + m) * 72 + kg * 8]);
            short8v B1 = *reinterpret_cast<const short8v*>(&sWbT[(16 * cq + m) * 72 + 32 + kg * 8]);
            float bb = sbb[16 * cq + m];
            float4v acc = {bb, bb, bb, bb};
            acc = __builtin_amdgcn_mfma_f32_16x16x32_bf16(C0, B0, acc, 0, 0, 0);
            acc = __builtin_amdgcn_mfma_f32_16x16x32_bf16(C1, B1, acc, 0, 0, 0);
#pragma unroll
            for (int i = 0; i < 4; ++i)
                h2[(size_t)(nt0 + kg * 4 + i) * 64 + 16 * cq + m] = fmaxf(acc[i], 0.0f);
        }
        __builtin_amdgcn_wave_barrier();
    }
}

// ---------------- Pool stage A: per-(graph, chunk) partial sums ----------------
__global__ __launch_bounds__(256) void poolA(const float* __restrict__ h2,
                                             const int* __restrict__ batch,
                                             float* __restrict__ partial) {  // [PCHUNK][N_GRAPHS][64]
    int g = blockIdx.x & (N_GRAPHS - 1);
    int c = blockIdx.x >> 7;

    int lo = 0, hi = N_NODES;
    while (lo < hi) { int mid = (lo + hi) >> 1; if (batch[mid] < g) lo = mid + 1; else hi = mid; }
    int start = lo;
    lo = start; hi = N_NODES;
    while (lo < hi) { int mid = (lo + hi) >> 1; if (batch[mid] < g + 1) lo = mid + 1; else hi = mid; }
    int end = lo;

    int len = end - start;
    int cs = start + (int)((long long)len * c / PCHUNK);
    int ce = start + (int)((long long)len * (c + 1) / PCHUNK);

    int j = threadIdx.x & 63;
    int r = threadIdx.x >> 6;
    float local = 0.0f;
    for (int n = cs + r; n < ce; n += 4)
        local += h2[(size_t)n * 64 + j];

    __shared__ float red[4][64];
    red[r][j] = local;
    __syncthreads();
    if (r == 0)
        partial[((size_t)c * N_GRAPHS + g) * 64 + j] = red[0][j] + red[1][j] + red[2][j] + red[3][j];
}

// ---------------- Pool stage B: reduce chunks, divide by count ----------------
__global__ __launch_bounds__(64) void poolB(const float* __restrict__ partial,
                                            const int* __restrict__ batch,
                                            float* __restrict__ out) {
    int g = blockIdx.x;
    int j = threadIdx.x;

    int lo = 0, hi = N_NODES;
    while (lo < hi) { int mid = (lo + hi) >> 1; if (batch[mid] < g) lo = mid + 1; else hi = mid; }
    int start = lo;
    lo = start; hi = N_NODES;
    while (lo < hi) { int mid = (lo + hi) >> 1; if (batch[mid] < g + 1) lo = mid + 1; else hi = mid; }
    int end = lo;

    float s = 0.0f;
#pragma unroll
    for (int c = 0; c < PCHUNK; ++c)
        s += partial[((size_t)c * N_GRAPHS + g) * 64 + j];
    float cnt = (float)((end - start) > 1 ? (end - start) : 1);
    out[g * 64 + j] = s / cnt;
}

extern "C" void kernel_launch(void* const* d_in, const int* in_sizes, int n_in,
                              void* d_out, int out_size, void* d_ws, size_t ws_size,
                              hipStream_t stream) {
    const float* x    = (const float*)d_in[0];
    const int*   ei   = (const int*)d_in[1];
    const int*   bat  = (const int*)d_in[2];
    const float* W1a  = (const float*)d_in[3];
    const float* b1a  = (const float*)d_in[4];
    const float* W1b  = (const float*)d_in[5];
    const float* b1b  = (const float*)d_in[6];
    const float* W2a  = (const float*)d_in[7];
    const float* b2a  = (const float*)d_in[8];
    const float* W2b  = (const float*)d_in[9];
    const float* b2b  = (const float*)d_in[10];
    float* out = (float*)d_out;

    const int* src = ei;
    const int* dst = ei + N_EDGES;

    char* ws = (char*)d_ws;
    auto alignup = [](size_t v) { return (v + 255) & ~(size_t)255; };
    int*   bcnt  = (int*)ws;                       ws += alignup((size_t)NBUCK * 16 * 4);
    int*   bbase = (int*)ws;                       ws += alignup((size_t)(NBUCK + 1) * 4);
    int*   off   = (int*)ws;                       ws += alignup((size_t)(N_NODES + 1) * 4);
    int*   esrc  = (int*)ws;                       ws += alignup((size_t)N_EDGES * 4);
    unsigned short* h1b = (unsigned short*)ws;     ws += alignup((size_t)N_NODES * HID * 2);
    float* partial = (float*)ws;                   ws += alignup((size_t)PCHUNK * N_GRAPHS * 64 * 4);
    // bbuf and h2 share a slab: bbuf dead before l2_mfma writes h2
    int2*  bbuf  = (int2*)ws;
    float* h2    = (float*)ws;

    hipMemsetAsync(bcnt, 0, (size_t)NBUCK * 16 * 4, stream);

    bucketA<<<NBLKA, BLKA, 0, stream>>>(src, dst, bcnt, bbuf);
    scanBuck<<<1, 256, 0, stream>>>(bcnt, bbase, off);
    bucketB<<<NBUCK, 1024, 0, stream>>>(bbuf, bcnt, bbase, off, esrc);

    l1_mfma<<<NBLK2, BLK2, 0, stream>>>(x, off, esrc, W1a, b1a, W1b, b1b, h1b);
    l2_mfma<<<NBLK2, BLK2, 0, stream>>>((const unsigned*)h1b, off, esrc, W2a, b2a, W2b, b2b, h2);

    poolA<<<N_GRAPHS * PCHUNK, 256, 0, stream>>>(h2, bat, partial);
    poolB<<<N_GRAPHS, 64, 0, stream>>>(partial, bat, out);
}